// Round 1
// baseline (2930.682 us; speedup 1.0000x reference)
//
#include <hip/hip_runtime.h>
#include <hip/hip_bf16.h>
#include <math.h>

#define DIM 1024
#define NUM_HEADS 16
#define HEAD_DIM 64
#define BATCH 4
#define SEQ 2048
#define EPS 1e-6f

// ---------------------------------------------------------------------------
// Kernel 1/4: C[M][N] = A[M][K] @ W[N][K]^T + bias[N]
// 64x64 tile, BK=16, 256 threads, 4x4 per thread. Pad-17 LDS rows: all LDS
// read/write conflicts are <=2-way (free on gfx950, m136).
// ---------------------------------------------------------------------------
__global__ __launch_bounds__(256) void gemm_bt_bias(
    const float* __restrict__ A, const float* __restrict__ W,
    const float* __restrict__ bias, float* __restrict__ C,
    int M, int N, int K)
{
    __shared__ float As[64][17];
    __shared__ float Bs[64][17];

    const int tid  = threadIdx.x;
    const int tx   = tid & 15;        // 0..15  (N direction)
    const int ty   = tid >> 4;        // 0..15  (M direction)
    const int lrow = tid >> 2;        // 0..63  staging row
    const int lcol = (tid & 3) * 4;   // 0,4,8,12 staging col

    const int row0 = blockIdx.y * 64;
    const int col0 = blockIdx.x * 64;

    float acc[4][4];
#pragma unroll
    for (int i = 0; i < 4; ++i)
#pragma unroll
        for (int j = 0; j < 4; ++j) acc[i][j] = 0.f;

    const float* Arow = A + (long)(row0 + lrow) * K + lcol;
    const float* Wrow = W + (long)(col0 + lrow) * K + lcol;

    for (int k0 = 0; k0 < K; k0 += 16) {
        float4 a4 = *(const float4*)(Arow + k0);
        float4 b4 = *(const float4*)(Wrow + k0);
        As[lrow][lcol + 0] = a4.x; As[lrow][lcol + 1] = a4.y;
        As[lrow][lcol + 2] = a4.z; As[lrow][lcol + 3] = a4.w;
        Bs[lrow][lcol + 0] = b4.x; Bs[lrow][lcol + 1] = b4.y;
        Bs[lrow][lcol + 2] = b4.z; Bs[lrow][lcol + 3] = b4.w;
        __syncthreads();

#pragma unroll
        for (int kk = 0; kk < 16; ++kk) {
            float a[4], b[4];
#pragma unroll
            for (int i = 0; i < 4; ++i) a[i] = As[ty * 4 + i][kk];
#pragma unroll
            for (int j = 0; j < 4; ++j) b[j] = Bs[tx * 4 + j][kk];
#pragma unroll
            for (int i = 0; i < 4; ++i)
#pragma unroll
                for (int j = 0; j < 4; ++j) acc[i][j] = fmaf(a[i], b[j], acc[i][j]);
        }
        __syncthreads();
    }

#pragma unroll
    for (int j = 0; j < 4; ++j) {
        float bj = bias[col0 + tx * 4 + j];
#pragma unroll
        for (int i = 0; i < 4; ++i) {
            C[(long)(row0 + ty * 4 + i) * N + col0 + tx * 4 + j] = acc[i][j] + bj;
        }
    }
}

// ---------------------------------------------------------------------------
// Kernel 2: per-(b,s,h) RMSNorm (q,k) + interleaved RoPE (q,k) + transpose
// all of q,k,v from qkv[B*S][3*DIM] into [B][H][S][D] layout.
// One 64-lane wave per (b,s,h) vector; lane = d.
// ---------------------------------------------------------------------------
__global__ __launch_bounds__(256) void norm_rope_split(
    const float* __restrict__ qkv,
    const float* __restrict__ cos_t, const float* __restrict__ sin_t,
    const float* __restrict__ qw, const float* __restrict__ kw,
    float* __restrict__ q, float* __restrict__ k, float* __restrict__ v)
{
    const int lane = threadIdx.x & 63;
    const int wave = threadIdx.x >> 6;                 // 0..3
    const long vec = (long)blockIdx.x * 4 + wave;      // 0 .. B*S*H-1
    const int h  = (int)(vec & (NUM_HEADS - 1));
    const long bs = vec >> 4;                          // b*SEQ + s
    const int s  = (int)(bs & (SEQ - 1));

    const float* base = qkv + bs * (3 * DIM);
    float qv = base[h * 64 + lane];
    float kv = base[DIM + h * 64 + lane];
    float vv = base[2 * DIM + h * 64 + lane];

    // RMS norm (butterfly sum of squares across 64 lanes)
    float sq = qv * qv;
    float sk = kv * kv;
#pragma unroll
    for (int m = 32; m; m >>= 1) {
        sq += __shfl_xor(sq, m, 64);
        sk += __shfl_xor(sk, m, 64);
    }
    float qn = qv * rsqrtf(sq * (1.f / 64.f) + EPS) * qw[lane];
    float kn = kv * rsqrtf(sk * (1.f / 64.f) + EPS) * kw[lane];

    // interleaved RoPE: rot[2i] = -x[2i+1], rot[2i+1] = x[2i]
    float c  = cos_t[s * 64 + lane];
    float sn = sin_t[s * 64 + lane];
    float qp = __shfl_xor(qn, 1, 64);
    float kp = __shfl_xor(kn, 1, 64);
    float rq = (lane & 1) ? qp : -qp;
    float rk = (lane & 1) ? kp : -kp;
    float qo = qn * c + rq * sn;
    float ko = kn * c + rk * sn;

    const int b = (int)(bs >> 11);                     // bs / SEQ
    const long off = (((long)b * NUM_HEADS + h) * SEQ + s) * 64 + lane;
    q[off] = qo;
    k[off] = ko;
    v[off] = vv;
}

// ---------------------------------------------------------------------------
// Kernel 3: flash attention. One block per (b,h, 64-row Q tile).
// Online softmax, K/V tiles of 64 in LDS, P via LDS for the PV product.
// q/k/v are [B][H][S][D]; output written as [B][S][H*D] (row-major for proj).
// ---------------------------------------------------------------------------
__global__ __launch_bounds__(256) void flash_attn(
    const float* __restrict__ q, const float* __restrict__ k,
    const float* __restrict__ v, float* __restrict__ out)
{
    __shared__ float Qs[64][65];
    __shared__ float Ks[64][65];
    __shared__ float Vs[64][65];
    __shared__ float Ps[64][65];

    const int bh = blockIdx.y;                   // 0..63
    const int b  = bh >> 4;
    const int h  = bh & 15;
    const int q0 = blockIdx.x * 64;

    const float* qb = q + (long)bh * SEQ * 64;
    const float* kb = k + (long)bh * SEQ * 64;
    const float* vb = v + (long)bh * SEQ * 64;

    const int tid  = threadIdx.x;
    const int tx   = tid & 15;
    const int ty   = tid >> 4;
    const int lrow = tid >> 2;                   // 0..63
    const int lcol = (tid & 3) * 16;             // 0,16,32,48

    const float scale = 0.125f;                  // 1/sqrt(64)

    // load Q tile (scale folded in)
    {
        const float* src = qb + (long)(q0 + lrow) * 64 + lcol;
#pragma unroll
        for (int c = 0; c < 16; c += 4) {
            float4 t = *(const float4*)(src + c);
            Qs[lrow][lcol + c + 0] = t.x * scale;
            Qs[lrow][lcol + c + 1] = t.y * scale;
            Qs[lrow][lcol + c + 2] = t.z * scale;
            Qs[lrow][lcol + c + 3] = t.w * scale;
        }
    }

    float o_acc[4][4];
    float m_i[4], l_i[4];
#pragma unroll
    for (int i = 0; i < 4; ++i) {
        m_i[i] = -INFINITY;
        l_i[i] = 0.f;
#pragma unroll
        for (int j = 0; j < 4; ++j) o_acc[i][j] = 0.f;
    }

    for (int kt = 0; kt < SEQ / 64; ++kt) {
        // stage K and V tiles
        {
            const float* ks = kb + (long)(kt * 64 + lrow) * 64 + lcol;
            const float* vs = vb + (long)(kt * 64 + lrow) * 64 + lcol;
#pragma unroll
            for (int c = 0; c < 16; c += 4) {
                float4 t = *(const float4*)(ks + c);
                Ks[lrow][lcol + c + 0] = t.x; Ks[lrow][lcol + c + 1] = t.y;
                Ks[lrow][lcol + c + 2] = t.z; Ks[lrow][lcol + c + 3] = t.w;
                float4 u = *(const float4*)(vs + c);
                Vs[lrow][lcol + c + 0] = u.x; Vs[lrow][lcol + c + 1] = u.y;
                Vs[lrow][lcol + c + 2] = u.z; Vs[lrow][lcol + c + 3] = u.w;
            }
        }
        __syncthreads();

        // S = Q @ K^T (scaled)
        float sacc[4][4];
#pragma unroll
        for (int i = 0; i < 4; ++i)
#pragma unroll
            for (int j = 0; j < 4; ++j) sacc[i][j] = 0.f;

#pragma unroll 8
        for (int d = 0; d < 64; ++d) {
            float a[4], bb[4];
#pragma unroll
            for (int i = 0; i < 4; ++i) a[i] = Qs[ty * 4 + i][d];
#pragma unroll
            for (int j = 0; j < 4; ++j) bb[j] = Ks[tx * 4 + j][d];
#pragma unroll
            for (int i = 0; i < 4; ++i)
#pragma unroll
                for (int j = 0; j < 4; ++j) sacc[i][j] = fmaf(a[i], bb[j], sacc[i][j]);
        }

        // online softmax update per row
#pragma unroll
        for (int i = 0; i < 4; ++i) {
            float rm = fmaxf(fmaxf(sacc[i][0], sacc[i][1]),
                             fmaxf(sacc[i][2], sacc[i][3]));
#pragma unroll
            for (int m = 1; m < 16; m <<= 1) rm = fmaxf(rm, __shfl_xor(rm, m, 64));
            float mn = fmaxf(m_i[i], rm);
            float alpha = __expf(m_i[i] - mn);
            float rs = 0.f;
#pragma unroll
            for (int j = 0; j < 4; ++j) {
                float p = __expf(sacc[i][j] - mn);
                sacc[i][j] = p;
                rs += p;
            }
#pragma unroll
            for (int m = 1; m < 16; m <<= 1) rs += __shfl_xor(rs, m, 64);
            l_i[i] = l_i[i] * alpha + rs;
            m_i[i] = mn;
#pragma unroll
            for (int j = 0; j < 4; ++j) o_acc[i][j] *= alpha;
#pragma unroll
            for (int j = 0; j < 4; ++j) Ps[ty * 4 + i][tx * 4 + j] = sacc[i][j];
        }
        __syncthreads();

        // O += P @ V
#pragma unroll 8
        for (int jj = 0; jj < 64; ++jj) {
            float p[4], vv2[4];
#pragma unroll
            for (int i = 0; i < 4; ++i) p[i] = Ps[ty * 4 + i][jj];
#pragma unroll
            for (int j = 0; j < 4; ++j) vv2[j] = Vs[jj][tx * 4 + j];
#pragma unroll
            for (int i = 0; i < 4; ++i)
#pragma unroll
                for (int j = 0; j < 4; ++j) o_acc[i][j] = fmaf(p[i], vv2[j], o_acc[i][j]);
        }
        __syncthreads();
    }

    // write out: [b][s][h*64+d]
#pragma unroll
    for (int i = 0; i < 4; ++i) {
        float inv_l = 1.f / l_i[i];
        long row = (long)b * SEQ + (q0 + ty * 4 + i);
#pragma unroll
        for (int j = 0; j < 4; ++j) {
            out[row * DIM + h * 64 + tx * 4 + j] = o_acc[i][j] * inv_l;
        }
    }
}

// ---------------------------------------------------------------------------
extern "C" void kernel_launch(void* const* d_in, const int* in_sizes, int n_in,
                              void* d_out, int out_size, void* d_ws, size_t ws_size,
                              hipStream_t stream)
{
    const float* x        = (const float*)d_in[0];
    const float* rope_cos = (const float*)d_in[1];
    const float* rope_sin = (const float*)d_in[2];
    const float* qkv_w    = (const float*)d_in[3];
    const float* qkv_b    = (const float*)d_in[4];
    const float* proj_w   = (const float*)d_in[5];
    const float* proj_b   = (const float*)d_in[6];
    const float* q_norm_w = (const float*)d_in[7];
    const float* k_norm_w = (const float*)d_in[8];
    float* out = (float*)d_out;

    const int M = BATCH * SEQ;          // 8192
    const long QKV_ELEMS = (long)M * 3 * DIM;        // 25165824
    const long HEAD_ELEMS = (long)BATCH * NUM_HEADS * SEQ * 64;  // 8388608

    float* ws    = (float*)d_ws;
    float* qkv   = ws;                              // 96 MB (reused as attn_out)
    float* qbuf  = ws + QKV_ELEMS;                  // 32 MB
    float* kbuf  = qbuf + HEAD_ELEMS;               // 32 MB
    float* vbuf  = kbuf + HEAD_ELEMS;               // 32 MB
    float* attno = ws;                              // reuse qkv region

    // 1) QKV GEMM: [8192][3072]
    {
        dim3 grid(3 * DIM / 64, M / 64);
        gemm_bt_bias<<<grid, 256, 0, stream>>>(x, qkv_w, qkv_b, qkv,
                                               M, 3 * DIM, DIM);
    }
    // 2) RMSNorm + RoPE + split/transpose
    {
        long nvec = (long)BATCH * SEQ * NUM_HEADS;   // 131072
        norm_rope_split<<<dim3(nvec / 4), 256, 0, stream>>>(
            qkv, rope_cos, rope_sin, q_norm_w, k_norm_w, qbuf, kbuf, vbuf);
    }
    // 3) flash attention -> attno [B][S][DIM]
    {
        dim3 grid(SEQ / 64, BATCH * NUM_HEADS);
        flash_attn<<<grid, 256, 0, stream>>>(qbuf, kbuf, vbuf, attno);
    }
    // 4) output projection
    {
        dim3 grid(DIM / 64, M / 64);
        gemm_bt_bias<<<grid, 256, 0, stream>>>(attno, proj_w, proj_b, out,
                                               M, DIM, DIM);
    }
}

// Round 2
// 487.768 us; speedup vs baseline: 6.0084x; 6.0084x over previous
//
#include <hip/hip_runtime.h>
#include <math.h>

#define DIM 1024
#define NH 16
#define HD 64
#define BATCH 4
#define SEQ 2048
#define EPS 1e-6f

typedef __attribute__((ext_vector_type(8))) short short8;
typedef __attribute__((ext_vector_type(4))) float float4v;

// round-to-nearest-even f32 -> bf16 bits
__device__ inline unsigned short f2bf(float f) {
    unsigned u = __float_as_uint(f);
    u += 0x7FFF + ((u >> 16) & 1);
    return (unsigned short)(u >> 16);
}

// async global->LDS, 16 bytes per lane. LDS dest must be wave-uniform-base + lane*16.
#define GLDS16(gp, lp) __builtin_amdgcn_global_load_lds( \
    (const __attribute__((address_space(1))) void*)(gp), \
    (__attribute__((address_space(3))) void*)(lp), 16, 0, 0)

// ---------------------------------------------------------------------------
// cast fp32 -> bf16 (x4 vectorized; n must be divisible by 4)
// ---------------------------------------------------------------------------
__global__ __launch_bounds__(256) void cast_f32_bf16(
    const float* __restrict__ src, unsigned short* __restrict__ dst, int n4)
{
    int i = blockIdx.x * 256 + threadIdx.x;
    if (i >= n4) return;
    float4 f = ((const float4*)src)[i];
    ushort4 o;
    o.x = f2bf(f.x); o.y = f2bf(f.y); o.z = f2bf(f.z); o.w = f2bf(f.w);
    ((ushort4*)dst)[i] = o;
}

// ---------------------------------------------------------------------------
// bf16 MFMA GEMM: C[M][N] = A[M][K] @ W[N][K]^T + bias[N], fp32 out.
// m97 structure: 128x128 tile, BK=32, 4 waves each owning 64x64 (4x4 MFMA tiles),
// global_load_lds width-16 staging, 64-B LDS rows (conflict-free b128 reads).
// ---------------------------------------------------------------------------
__global__ __launch_bounds__(256) void gemm_mfma_bt(
    const unsigned short* __restrict__ A, const unsigned short* __restrict__ W,
    const float* __restrict__ bias, float* __restrict__ C,
    int M, int N, int K)
{
    __shared__ __align__(16) unsigned short As[128 * 32];
    __shared__ __align__(16) unsigned short Bs[128 * 32];

    const int t    = threadIdx.x;
    const int lane = t & 63;
    const int w    = t >> 6;
    const int row0 = blockIdx.y * 128;
    const int col0 = blockIdx.x * 128;
    const int wr   = (w & 1) * 64;
    const int wc   = (w >> 1) * 64;

    float4v acc[4][4];
#pragma unroll
    for (int i = 0; i < 4; ++i)
#pragma unroll
        for (int j = 0; j < 4; ++j) acc[i][j] = (float4v){0.f, 0.f, 0.f, 0.f};

    // staging: 8192 B per tile = 2 x 16B chunks per thread
    const int off1 = t * 16, off2 = 4096 + t * 16;
    const int r1 = off1 >> 6, c1 = off1 & 63;
    const int r2 = off2 >> 6, c2 = off2 & 63;
    const char* Ab = (const char*)A + (long)row0 * K * 2;
    const char* Wb = (const char*)W + (long)col0 * K * 2;
    const long  ks = (long)K * 2;   // row stride bytes

    for (int k0 = 0; k0 < K; k0 += 32) {
        const long kb = (long)k0 * 2;
        GLDS16(Ab + (long)r1 * ks + kb + c1, (char*)As + off1);
        GLDS16(Ab + (long)r2 * ks + kb + c2, (char*)As + off2);
        GLDS16(Wb + (long)r1 * ks + kb + c1, (char*)Bs + off1);
        GLDS16(Wb + (long)r2 * ks + kb + c2, (char*)Bs + off2);
        __syncthreads();

        short8 af[4], bfr[4];
#pragma unroll
        for (int i = 0; i < 4; ++i)
            af[i] = *(const short8*)&As[(wr + i * 16 + (lane & 15)) * 32 + (lane >> 4) * 8];
#pragma unroll
        for (int j = 0; j < 4; ++j)
            bfr[j] = *(const short8*)&Bs[(wc + j * 16 + (lane & 15)) * 32 + (lane >> 4) * 8];
#pragma unroll
        for (int i = 0; i < 4; ++i)
#pragma unroll
            for (int j = 0; j < 4; ++j)
                acc[i][j] = __builtin_amdgcn_mfma_f32_16x16x32_bf16(af[i], bfr[j], acc[i][j], 0, 0, 0);
        __syncthreads();
    }

    const int qd = lane >> 4, cl = lane & 15;
#pragma unroll
    for (int j = 0; j < 4; ++j) {
        const int col = col0 + wc + j * 16 + cl;
        const float bj = bias[col];
#pragma unroll
        for (int i = 0; i < 4; ++i) {
            const long rr = row0 + wr + i * 16 + qd * 4;
#pragma unroll
            for (int r = 0; r < 4; ++r)
                C[(rr + r) * (long)N + col] = acc[i][j][r] + bj;
        }
    }
}

// ---------------------------------------------------------------------------
// RMSNorm (q,k) + interleaved RoPE + split. One wave per (b,s,h), lane = d.
// Outputs bf16: q [bh][s][d] (pre-scaled by 1/8), k [bh][s][d], vt [bh][d][s].
// ---------------------------------------------------------------------------
__global__ __launch_bounds__(256) void norm_rope_split(
    const float* __restrict__ qkv,
    const float* __restrict__ cos_t, const float* __restrict__ sin_t,
    const float* __restrict__ qw, const float* __restrict__ kw,
    unsigned short* __restrict__ q, unsigned short* __restrict__ k,
    unsigned short* __restrict__ vt)
{
    const int lane = threadIdx.x & 63;
    const int wave = threadIdx.x >> 6;
    const long vec = (long)blockIdx.x * 4 + wave;      // 0 .. B*S*H-1
    const int h  = (int)(vec & (NH - 1));
    const long bs = vec >> 4;                          // b*SEQ + s
    const int s  = (int)(bs & (SEQ - 1));
    const int b  = (int)(bs >> 11);

    const float* base = qkv + bs * (3 * DIM);
    float qv = base[h * 64 + lane];
    float kv = base[DIM + h * 64 + lane];
    float vv = base[2 * DIM + h * 64 + lane];

    float sq = qv * qv, sk = kv * kv;
#pragma unroll
    for (int m = 32; m; m >>= 1) {
        sq += __shfl_xor(sq, m, 64);
        sk += __shfl_xor(sk, m, 64);
    }
    float qn = qv * rsqrtf(sq * (1.f / 64.f) + EPS) * qw[lane];
    float kn = kv * rsqrtf(sk * (1.f / 64.f) + EPS) * kw[lane];

    float c  = cos_t[s * 64 + lane];
    float sn = sin_t[s * 64 + lane];
    float qp = __shfl_xor(qn, 1, 64);
    float kp = __shfl_xor(kn, 1, 64);
    float rq = (lane & 1) ? qp : -qp;
    float rk = (lane & 1) ? kp : -kp;
    float qo = (qn * c + rq * sn) * 0.125f;            // fold 1/sqrt(64)
    float ko = kn * c + rk * sn;

    const long bh = (long)b * NH + h;
    const long off = (bh * SEQ + s) * 64 + lane;
    q[off] = f2bf(qo);
    k[off] = f2bf(ko);
    vt[(bh * 64 + lane) * SEQ + s] = f2bf(vv);
}

// ---------------------------------------------------------------------------
// MFMA flash attention. Block = 4 waves, 64 Q-rows (16 per wave), K-tiles of 64.
// All tiles stored as two [64][32] bf16 halves (64-B rows -> conflict-free b128,
// and global_load_lds-compatible). P goes through per-wave LDS (C-layout ->
// A-layout), V is pre-transposed so PV B-operand reads are contiguous.
// ---------------------------------------------------------------------------
__global__ __launch_bounds__(256) void flash_mfma(
    const unsigned short* __restrict__ q, const unsigned short* __restrict__ k,
    const unsigned short* __restrict__ vt, unsigned short* __restrict__ out)
{
    __shared__ __align__(16) unsigned short Qs[2][64 * 32];
    __shared__ __align__(16) unsigned short Ks[2][64 * 32];
    __shared__ __align__(16) unsigned short Vts[2][64 * 32];
    __shared__ __align__(16) unsigned short Ps[4][2][16 * 32];

    const int t    = threadIdx.x;
    const int lane = t & 63;
    const int w    = t >> 6;
    const int bh   = blockIdx.y;            // b*16 + h
    const int b    = bh >> 4;
    const int h    = bh & 15;
    const int q0   = blockIdx.x * 64;

    const char* qb  = (const char*)(q  + (long)bh * SEQ * 64);
    const char* kb  = (const char*)(k  + (long)bh * SEQ * 64);
    const char* vtb = (const char*)(vt + (long)bh * 64 * SEQ);

    // stage Q tile once: halves of [64][32], 64-B rows
    {
        const int off = t * 16, row = off >> 6, cb = off & 63;
#pragma unroll
        for (int hf = 0; hf < 2; ++hf)
            GLDS16(qb + (long)(q0 + row) * 128 + hf * 64 + cb, (char*)Qs[hf] + off);
    }
    __syncthreads();

    short8 aq[2];
#pragma unroll
    for (int c = 0; c < 2; ++c)
        aq[c] = *(const short8*)&Qs[c][(w * 16 + (lane & 15)) * 32 + (lane >> 4) * 8];

    float4v o[4];
    float m_i[4], l_i[4];
#pragma unroll
    for (int d = 0; d < 4; ++d) o[d] = (float4v){0.f, 0.f, 0.f, 0.f};
#pragma unroll
    for (int r = 0; r < 4; ++r) { m_i[r] = -INFINITY; l_i[r] = 0.f; }

    const int soff = t * 16, srow = soff >> 6, scb = soff & 63;

    for (int kt = 0; kt < SEQ / 64; ++kt) {
        // stage K [krow][d] and Vt [d][krow] tiles (2 halves each)
#pragma unroll
        for (int hf = 0; hf < 2; ++hf) {
            GLDS16(kb + (long)(kt * 64 + srow) * 128 + hf * 64 + scb, (char*)Ks[hf] + soff);
            GLDS16(vtb + (long)srow * (SEQ * 2) + kt * 128 + hf * 64 + scb, (char*)Vts[hf] + soff);
        }
        __syncthreads();

        // S = Q @ K^T  (scale pre-folded into Q)
        float4v sa[4];
#pragma unroll
        for (int j = 0; j < 4; ++j) {
            short8 b0 = *(const short8*)&Ks[0][(j * 16 + (lane & 15)) * 32 + (lane >> 4) * 8];
            short8 b1 = *(const short8*)&Ks[1][(j * 16 + (lane & 15)) * 32 + (lane >> 4) * 8];
            float4v z = (float4v){0.f, 0.f, 0.f, 0.f};
            z = __builtin_amdgcn_mfma_f32_16x16x32_bf16(aq[0], b0, z, 0, 0, 0);
            sa[j] = __builtin_amdgcn_mfma_f32_16x16x32_bf16(aq[1], b1, z, 0, 0, 0);
        }

        // online softmax; lane holds rows {(lane>>4)*4+r}, cols {j*16 + (lane&15)}
#pragma unroll
        for (int r = 0; r < 4; ++r) {
            float rm = fmaxf(fmaxf(sa[0][r], sa[1][r]), fmaxf(sa[2][r], sa[3][r]));
#pragma unroll
            for (int m = 1; m < 16; m <<= 1) rm = fmaxf(rm, __shfl_xor(rm, m, 64));
            float mn = fmaxf(m_i[r], rm);
            float alpha = __expf(m_i[r] - mn);
            m_i[r] = mn;
            float rs = 0.f;
            float p[4];
#pragma unroll
            for (int j = 0; j < 4; ++j) { p[j] = __expf(sa[j][r] - mn); rs += p[j]; }
#pragma unroll
            for (int m = 1; m < 16; m <<= 1) rs += __shfl_xor(rs, m, 64);
            l_i[r] = l_i[r] * alpha + rs;
#pragma unroll
            for (int d = 0; d < 4; ++d) o[d][r] *= alpha;
            // P -> per-wave LDS (C-layout write)
#pragma unroll
            for (int j = 0; j < 4; ++j)
                Ps[w][j >> 1][((lane >> 4) * 4 + r) * 32 + (j & 1) * 16 + (lane & 15)] = f2bf(p[j]);
        }

        // wave-private P: only need this wave's DS ops drained, not a barrier
        asm volatile("s_waitcnt lgkmcnt(0)" ::: "memory");

        short8 pa[2];
#pragma unroll
        for (int c = 0; c < 2; ++c)
            pa[c] = *(const short8*)&Ps[w][c][(lane & 15) * 32 + (lane >> 4) * 8];

        // O += P @ V   (B-operand from transposed V)
#pragma unroll
        for (int d = 0; d < 4; ++d) {
            short8 b0 = *(const short8*)&Vts[0][(d * 16 + (lane & 15)) * 32 + (lane >> 4) * 8];
            short8 b1 = *(const short8*)&Vts[1][(d * 16 + (lane & 15)) * 32 + (lane >> 4) * 8];
            o[d] = __builtin_amdgcn_mfma_f32_16x16x32_bf16(pa[0], b0, o[d], 0, 0, 0);
            o[d] = __builtin_amdgcn_mfma_f32_16x16x32_bf16(pa[1], b1, o[d], 0, 0, 0);
        }
        __syncthreads();   // before next tile overwrites Ks/Vts
    }

    // epilogue: out[b][q0+row][h*64+col] in bf16 for the proj GEMM
#pragma unroll
    for (int r = 0; r < 4; ++r) {
        float inv = 1.f / l_i[r];
        long row = q0 + w * 16 + (lane >> 4) * 4 + r;
        long rb = ((long)b * SEQ + row) * DIM + h * 64;
#pragma unroll
        for (int d = 0; d < 4; ++d)
            out[rb + d * 16 + (lane & 15)] = f2bf(o[d][r] * inv);
    }
}

// ---------------------------------------------------------------------------
extern "C" void kernel_launch(void* const* d_in, const int* in_sizes, int n_in,
                              void* d_out, int out_size, void* d_ws, size_t ws_size,
                              hipStream_t stream)
{
    const float* x        = (const float*)d_in[0];
    const float* rope_cos = (const float*)d_in[1];
    const float* rope_sin = (const float*)d_in[2];
    const float* qkv_w    = (const float*)d_in[3];
    const float* qkv_b    = (const float*)d_in[4];
    const float* proj_w   = (const float*)d_in[5];
    const float* proj_b   = (const float*)d_in[6];
    const float* q_norm_w = (const float*)d_in[7];
    const float* k_norm_w = (const float*)d_in[8];
    float* outp = (float*)d_out;

    const int M = BATCH * SEQ;                         // 8192
    char* p = (char*)d_ws;
    float* qkvf = (float*)p;          p += (long)M * 3 * DIM * 4;      // 100.7 MB
    unsigned short* xb    = (unsigned short*)p; p += (long)M * DIM * 2;        // 16.8 MB
    unsigned short* qkvwb = (unsigned short*)p; p += (long)3 * DIM * DIM * 2;  // 6.3 MB
    unsigned short* projwb= (unsigned short*)p; p += (long)DIM * DIM * 2;      // 2.1 MB
    unsigned short* qb    = (unsigned short*)p; p += (long)M * DIM * 2;
    unsigned short* kbuf  = (unsigned short*)p; p += (long)M * DIM * 2;
    unsigned short* vtb   = (unsigned short*)p; p += (long)M * DIM * 2;
    unsigned short* attno = (unsigned short*)p; p += (long)M * DIM * 2;

    // casts
    cast_f32_bf16<<<dim3((M * DIM / 4) / 256), 256, 0, stream>>>(x, xb, M * DIM / 4);
    cast_f32_bf16<<<dim3((3 * DIM * DIM / 4) / 256), 256, 0, stream>>>(qkv_w, qkvwb, 3 * DIM * DIM / 4);
    cast_f32_bf16<<<dim3((DIM * DIM / 4) / 256), 256, 0, stream>>>(proj_w, projwb, DIM * DIM / 4);

    // 1) QKV GEMM (bf16 MFMA, fp32 out)
    gemm_mfma_bt<<<dim3(3 * DIM / 128, M / 128), 256, 0, stream>>>(
        xb, qkvwb, qkv_b, qkvf, M, 3 * DIM, DIM);

    // 2) RMSNorm + RoPE + split (bf16 q scaled, k, v transposed)
    norm_rope_split<<<dim3(BATCH * SEQ * NH / 4), 256, 0, stream>>>(
        qkvf, rope_cos, rope_sin, q_norm_w, k_norm_w, qb, kbuf, vtb);

    // 3) MFMA flash attention -> attno (bf16, [B][S][DIM])
    flash_mfma<<<dim3(SEQ / 64, BATCH * NH), 256, 0, stream>>>(qb, kbuf, vtb, attno);

    // 4) output projection (bf16 MFMA, fp32 out)
    gemm_mfma_bt<<<dim3(DIM / 128, M / 128), 256, 0, stream>>>(
        attno, projwb, proj_b, outp, M, DIM, DIM);
}

// Round 3
// 385.496 us; speedup vs baseline: 7.6024x; 1.2653x over previous
//
#include <hip/hip_runtime.h>
#include <math.h>
#include <type_traits>

#define DIM 1024
#define NH 16
#define HD 64
#define BATCH 4
#define SEQ 2048
#define EPS 1e-6f

typedef __attribute__((ext_vector_type(8))) short short8;
typedef __attribute__((ext_vector_type(4))) float float4v;

// round-to-nearest-even f32 -> bf16 bits
__device__ inline unsigned short f2bf(float f) {
    unsigned u = __float_as_uint(f);
    u += 0x7FFF + ((u >> 16) & 1);
    return (unsigned short)(u >> 16);
}
__device__ inline float bf2f(unsigned short b) {
    return __uint_as_float(((unsigned)b) << 16);
}

// async global->LDS, 16 bytes per lane. LDS dest must be wave-uniform base + lane*16.
#define GLDS16(gp, lp) __builtin_amdgcn_global_load_lds( \
    (const __attribute__((address_space(1))) void*)(gp), \
    (__attribute__((address_space(3))) void*)(lp), 16, 0, 0)

// ---------------------------------------------------------------------------
// cast fp32 -> bf16 (x4 vectorized)
// ---------------------------------------------------------------------------
__global__ __launch_bounds__(256) void cast_f32_bf16(
    const float* __restrict__ src, unsigned short* __restrict__ dst, int n4)
{
    int i = blockIdx.x * 256 + threadIdx.x;
    if (i >= n4) return;
    float4 f = ((const float4*)src)[i];
    ushort4 o;
    o.x = f2bf(f.x); o.y = f2bf(f.y); o.z = f2bf(f.z); o.w = f2bf(f.w);
    ((ushort4*)dst)[i] = o;
}

// ---------------------------------------------------------------------------
// bf16 MFMA GEMM: C[M][N] = A[M][K] @ W[N][K]^T + bias[N]. OT = float or
// unsigned short (bf16 out). m97 structure: 128x128 tile, BK=32, 4 waves.
// ---------------------------------------------------------------------------
template <typename OT>
__global__ __launch_bounds__(256) void gemm_mfma_bt(
    const unsigned short* __restrict__ A, const unsigned short* __restrict__ W,
    const float* __restrict__ bias, OT* __restrict__ C,
    int M, int N, int K)
{
    __shared__ __align__(16) unsigned short As[128 * 32];
    __shared__ __align__(16) unsigned short Bs[128 * 32];

    const int t    = threadIdx.x;
    const int lane = t & 63;
    const int w    = t >> 6;
    const int row0 = blockIdx.y * 128;
    const int col0 = blockIdx.x * 128;
    const int wr   = (w & 1) * 64;
    const int wc   = (w >> 1) * 64;

    float4v acc[4][4];
#pragma unroll
    for (int i = 0; i < 4; ++i)
#pragma unroll
        for (int j = 0; j < 4; ++j) acc[i][j] = (float4v){0.f, 0.f, 0.f, 0.f};

    const int off1 = t * 16, off2 = 4096 + t * 16;
    const int r1 = off1 >> 6, c1 = off1 & 63;
    const int r2 = off2 >> 6, c2 = off2 & 63;
    const char* Ab = (const char*)A + (long)row0 * K * 2;
    const char* Wb = (const char*)W + (long)col0 * K * 2;
    const long  ks = (long)K * 2;

    for (int k0 = 0; k0 < K; k0 += 32) {
        const long kb = (long)k0 * 2;
        GLDS16(Ab + (long)r1 * ks + kb + c1, (char*)As + off1);
        GLDS16(Ab + (long)r2 * ks + kb + c2, (char*)As + off2);
        GLDS16(Wb + (long)r1 * ks + kb + c1, (char*)Bs + off1);
        GLDS16(Wb + (long)r2 * ks + kb + c2, (char*)Bs + off2);
        __syncthreads();

        short8 af[4], bfr[4];
#pragma unroll
        for (int i = 0; i < 4; ++i)
            af[i] = *(const short8*)&As[(wr + i * 16 + (lane & 15)) * 32 + (lane >> 4) * 8];
#pragma unroll
        for (int j = 0; j < 4; ++j)
            bfr[j] = *(const short8*)&Bs[(wc + j * 16 + (lane & 15)) * 32 + (lane >> 4) * 8];
#pragma unroll
        for (int i = 0; i < 4; ++i)
#pragma unroll
            for (int j = 0; j < 4; ++j)
                acc[i][j] = __builtin_amdgcn_mfma_f32_16x16x32_bf16(af[i], bfr[j], acc[i][j], 0, 0, 0);
        __syncthreads();
    }

    const int qd = lane >> 4, cl = lane & 15;
#pragma unroll
    for (int j = 0; j < 4; ++j) {
        const int col = col0 + wc + j * 16 + cl;
        const float bj = bias[col];
#pragma unroll
        for (int i = 0; i < 4; ++i) {
            const long rr = row0 + wr + i * 16 + qd * 4;
#pragma unroll
            for (int r = 0; r < 4; ++r) {
                float val = acc[i][j][r] + bj;
                if constexpr (std::is_same<OT, unsigned short>::value)
                    C[(rr + r) * (long)N + col] = f2bf(val);
                else
                    C[(rr + r) * (long)N + col] = val;
            }
        }
    }
}

// ---------------------------------------------------------------------------
// RMSNorm (q,k) + interleaved RoPE + split, bf16 in / bf16 out.
// Block = (bh, 64-s chunk). lane = d, wave w handles s = s0+w*16+i.
// q [bh][s][d] (pre-scaled by 0.125), k [bh][s][d], vt [bh][d][s] via LDS
// transpose so ALL global writes are coalesced.
// ---------------------------------------------------------------------------
__global__ __launch_bounds__(256) void norm_rope_split(
    const unsigned short* __restrict__ qkv,
    const float* __restrict__ cos_t, const float* __restrict__ sin_t,
    const float* __restrict__ qw, const float* __restrict__ kw,
    unsigned short* __restrict__ q, unsigned short* __restrict__ k,
    unsigned short* __restrict__ vt)
{
    __shared__ unsigned short vs[64][68];   // [d][s_local], 136-B rows

    const int lane = threadIdx.x & 63;
    const int w    = threadIdx.x >> 6;
    const int bh   = blockIdx.y;
    const int b    = bh >> 4;
    const int h    = bh & 15;
    const int s0   = blockIdx.x * 64;

    const float qwl = qw[lane], kwl = kw[lane];

#pragma unroll 4
    for (int i = 0; i < 16; ++i) {
        const int sl = w * 16 + i;          // 0..63
        const int s  = s0 + sl;
        const long bs = (long)b * SEQ + s;
        const unsigned short* base = qkv + bs * (3 * DIM) + h * 64 + lane;
        float qv = bf2f(base[0]);
        float kv = bf2f(base[DIM]);
        float vv = bf2f(base[2 * DIM]);

        float sq = qv * qv, sk = kv * kv;
#pragma unroll
        for (int m = 32; m; m >>= 1) {
            sq += __shfl_xor(sq, m, 64);
            sk += __shfl_xor(sk, m, 64);
        }
        float qn = qv * rsqrtf(sq * (1.f / 64.f) + EPS) * qwl;
        float kn = kv * rsqrtf(sk * (1.f / 64.f) + EPS) * kwl;

        float c  = cos_t[s * 64 + lane];
        float sn = sin_t[s * 64 + lane];
        float qp = __shfl_xor(qn, 1, 64);
        float kp = __shfl_xor(kn, 1, 64);
        float rq = (lane & 1) ? qp : -qp;
        float rk = (lane & 1) ? kp : -kp;
        float qo = (qn * c + rq * sn) * 0.125f;     // fold 1/sqrt(64)
        float ko = kn * c + rk * sn;

        const long off = ((long)bh * SEQ + s) * 64 + lane;
        q[off] = f2bf(qo);
        k[off] = f2bf(ko);
        vs[lane][sl] = f2bf(vv);
    }
    __syncthreads();

    // transpose-out: thread -> (d = t>>2, s-quarter = t&3), 32 B per thread
    const int d  = threadIdx.x >> 2;
    const int sq = threadIdx.x & 3;
    ushort4 a0 = *(const ushort4*)&vs[d][sq * 16 + 0];
    ushort4 a1 = *(const ushort4*)&vs[d][sq * 16 + 4];
    ushort4 a2 = *(const ushort4*)&vs[d][sq * 16 + 8];
    ushort4 a3 = *(const ushort4*)&vs[d][sq * 16 + 12];
    unsigned short* dst = vt + ((long)bh * 64 + d) * SEQ + s0 + sq * 16;
    *(ushort4*)(dst + 0)  = a0;
    *(ushort4*)(dst + 4)  = a1;
    *(ushort4*)(dst + 8)  = a2;
    *(ushort4*)(dst + 12) = a3;
}

// ---------------------------------------------------------------------------
// MFMA flash attention, no-max softmax (|q.k|/8 <= 8 by Cauchy-Schwarz since
// rows are RMS-normalized: exp never overflows; sum <= 6.1e6 fits fp32).
// Row-sum reductions deferred to epilogue. Ps rows padded to 40 shorts
// (80 B: 16-B aligned b128 reads, quad bank-shift 16 -> <=4-way writes).
// ---------------------------------------------------------------------------
__global__ __launch_bounds__(256) void flash_mfma(
    const unsigned short* __restrict__ q, const unsigned short* __restrict__ k,
    const unsigned short* __restrict__ vt, unsigned short* __restrict__ out)
{
    __shared__ __align__(16) unsigned short Qs[2][64 * 32];
    __shared__ __align__(16) unsigned short Ks[2][64 * 32];
    __shared__ __align__(16) unsigned short Vts[2][64 * 32];
    __shared__ __align__(16) unsigned short Ps[4][2][16 * 40];

    const int t    = threadIdx.x;
    const int lane = t & 63;
    const int w    = t >> 6;
    const int bh   = blockIdx.y;
    const int b    = bh >> 4;
    const int h    = bh & 15;
    const int q0   = blockIdx.x * 64;
    const int cl   = lane & 15;
    const int quad = lane >> 4;

    const char* qb  = (const char*)(q  + (long)bh * SEQ * 64);
    const char* kb  = (const char*)(k  + (long)bh * SEQ * 64);
    const char* vtb = (const char*)(vt + (long)bh * 64 * SEQ);

    {
        const int off = t * 16, row = off >> 6, cb = off & 63;
#pragma unroll
        for (int hf = 0; hf < 2; ++hf)
            GLDS16(qb + (long)(q0 + row) * 128 + hf * 64 + cb, (char*)Qs[hf] + off);
    }
    __syncthreads();

    short8 aq[2];
#pragma unroll
    for (int c = 0; c < 2; ++c)
        aq[c] = *(const short8*)&Qs[c][(w * 16 + cl) * 32 + quad * 8];

    float4v o[4];
    float lacc[4];
#pragma unroll
    for (int d = 0; d < 4; ++d) o[d] = (float4v){0.f, 0.f, 0.f, 0.f};
#pragma unroll
    for (int r = 0; r < 4; ++r) lacc[r] = 0.f;

    const int soff = t * 16, srow = soff >> 6, scb = soff & 63;

    for (int kt = 0; kt < SEQ / 64; ++kt) {
#pragma unroll
        for (int hf = 0; hf < 2; ++hf) {
            GLDS16(kb + (long)(kt * 64 + srow) * 128 + hf * 64 + scb, (char*)Ks[hf] + soff);
            GLDS16(vtb + (long)srow * (SEQ * 2) + kt * 128 + hf * 64 + scb, (char*)Vts[hf] + soff);
        }
        __syncthreads();

        // S = Q @ K^T (scale pre-folded into Q)
        float4v sa[4];
#pragma unroll
        for (int j = 0; j < 4; ++j) {
            short8 b0 = *(const short8*)&Ks[0][(j * 16 + cl) * 32 + quad * 8];
            short8 b1 = *(const short8*)&Ks[1][(j * 16 + cl) * 32 + quad * 8];
            float4v z = (float4v){0.f, 0.f, 0.f, 0.f};
            z = __builtin_amdgcn_mfma_f32_16x16x32_bf16(aq[0], b0, z, 0, 0, 0);
            sa[j] = __builtin_amdgcn_mfma_f32_16x16x32_bf16(aq[1], b1, z, 0, 0, 0);
        }

        // P = exp(S); accumulate private row partial sums; C-layout -> LDS
#pragma unroll
        for (int j = 0; j < 4; ++j) {
#pragma unroll
            for (int r = 0; r < 4; ++r) {
                float p = __expf(sa[j][r]);
                lacc[r] += p;
                Ps[w][j >> 1][(quad * 4 + r) * 40 + (j & 1) * 16 + cl] = f2bf(p);
            }
        }
        // wave-private P: drain own DS ops, no barrier needed
        asm volatile("s_waitcnt lgkmcnt(0)" ::: "memory");

        short8 pa[2];
#pragma unroll
        for (int c = 0; c < 2; ++c)
            pa[c] = *(const short8*)&Ps[w][c][cl * 40 + quad * 8];

        // O += P @ V
#pragma unroll
        for (int d = 0; d < 4; ++d) {
            short8 b0 = *(const short8*)&Vts[0][(d * 16 + cl) * 32 + quad * 8];
            short8 b1 = *(const short8*)&Vts[1][(d * 16 + cl) * 32 + quad * 8];
            o[d] = __builtin_amdgcn_mfma_f32_16x16x32_bf16(pa[0], b0, o[d], 0, 0, 0);
            o[d] = __builtin_amdgcn_mfma_f32_16x16x32_bf16(pa[1], b1, o[d], 0, 0, 0);
        }
        __syncthreads();
    }

    // epilogue: reduce row sums over the 16 col-lanes, normalize, store bf16
#pragma unroll
    for (int r = 0; r < 4; ++r) {
#pragma unroll
        for (int m = 1; m < 16; m <<= 1) lacc[r] += __shfl_xor(lacc[r], m, 64);
        float inv = 1.f / lacc[r];
        long row = q0 + w * 16 + quad * 4 + r;
        long rb = ((long)b * SEQ + row) * DIM + h * 64;
#pragma unroll
        for (int d = 0; d < 4; ++d)
            out[rb + d * 16 + cl] = f2bf(o[d][r] * inv);
    }
}

// ---------------------------------------------------------------------------
extern "C" void kernel_launch(void* const* d_in, const int* in_sizes, int n_in,
                              void* d_out, int out_size, void* d_ws, size_t ws_size,
                              hipStream_t stream)
{
    const float* x        = (const float*)d_in[0];
    const float* rope_cos = (const float*)d_in[1];
    const float* rope_sin = (const float*)d_in[2];
    const float* qkv_w    = (const float*)d_in[3];
    const float* qkv_b    = (const float*)d_in[4];
    const float* proj_w   = (const float*)d_in[5];
    const float* proj_b   = (const float*)d_in[6];
    const float* q_norm_w = (const float*)d_in[7];
    const float* k_norm_w = (const float*)d_in[8];
    float* outp = (float*)d_out;

    const int M = BATCH * SEQ;                         // 8192
    char* p = (char*)d_ws;
    unsigned short* qkvb  = (unsigned short*)p; p += (long)M * 3 * DIM * 2;    // 50.3 MB
    unsigned short* xb    = (unsigned short*)p; p += (long)M * DIM * 2;        // 16.8 MB
    unsigned short* qkvwb = (unsigned short*)p; p += (long)3 * DIM * DIM * 2;  // 6.3 MB
    unsigned short* projwb= (unsigned short*)p; p += (long)DIM * DIM * 2;      // 2.1 MB
    unsigned short* qb    = (unsigned short*)p; p += (long)M * DIM * 2;
    unsigned short* kbuf  = (unsigned short*)p; p += (long)M * DIM * 2;
    unsigned short* vtb   = (unsigned short*)p; p += (long)M * DIM * 2;
    unsigned short* attno = (unsigned short*)p; p += (long)M * DIM * 2;

    cast_f32_bf16<<<dim3((M * DIM / 4) / 256), 256, 0, stream>>>(x, xb, M * DIM / 4);
    cast_f32_bf16<<<dim3((3 * DIM * DIM / 4) / 256), 256, 0, stream>>>(qkv_w, qkvwb, 3 * DIM * DIM / 4);
    cast_f32_bf16<<<dim3((DIM * DIM / 4) / 256), 256, 0, stream>>>(proj_w, projwb, DIM * DIM / 4);

    // 1) QKV GEMM (bf16 MFMA, bf16 out)
    gemm_mfma_bt<unsigned short><<<dim3(3 * DIM / 128, M / 128), 256, 0, stream>>>(
        xb, qkvwb, qkv_b, qkvb, M, 3 * DIM, DIM);

    // 2) RMSNorm + RoPE + split (coalesced vt transpose via LDS)
    norm_rope_split<<<dim3(SEQ / 64, BATCH * NH), 256, 0, stream>>>(
        qkvb, rope_cos, rope_sin, q_norm_w, k_norm_w, qb, kbuf, vtb);

    // 3) MFMA flash attention (no-max softmax) -> attno bf16 [B][S][DIM]
    flash_mfma<<<dim3(SEQ / 64, BATCH * NH), 256, 0, stream>>>(qb, kbuf, vtb, attno);

    // 4) output projection (bf16 MFMA, fp32 out)
    gemm_mfma_bt<float><<<dim3(DIM / 128, M / 128), 256, 0, stream>>>(
        attno, projwb, proj_b, outp, M, DIM, DIM);
}

// Round 4
// 366.230 us; speedup vs baseline: 8.0023x; 1.0526x over previous
//
#include <hip/hip_runtime.h>
#include <math.h>
#include <type_traits>

#define DIM 1024
#define NH 16
#define HD 64
#define BATCH 4
#define SEQ 2048
#define EPS 1e-6f

typedef __attribute__((ext_vector_type(8))) short short8;
typedef __attribute__((ext_vector_type(4))) short short4v;
typedef __attribute__((ext_vector_type(4))) float float4v;

// round-to-nearest-even f32 -> bf16 bits
__device__ inline unsigned short f2bf(float f) {
    unsigned u = __float_as_uint(f);
    u += 0x7FFF + ((u >> 16) & 1);
    return (unsigned short)(u >> 16);
}
__device__ inline float bf2f(unsigned short b) {
    return __uint_as_float(((unsigned)b) << 16);
}
// pack two f32 -> two bf16 (round-half-up ~= RNE except exact ties): 2 adds + 1 perm
__device__ inline unsigned pk2bf(float lo, float hi) {
    unsigned ul = __float_as_uint(lo) + 0x8000u;
    unsigned uh = __float_as_uint(hi) + 0x8000u;
    return __builtin_amdgcn_perm(uh, ul, 0x07060302u);  // {uh.b3,uh.b2,ul.b3,ul.b2}
}

// 16x16x16 bf16 MFMA (instruction exists on gfx950 per ISA; builtin name varies)
#if __has_builtin(__builtin_amdgcn_mfma_f32_16x16x16bf16_1k)
__device__ inline float4v mfma16(short4v a, short4v b, float4v c) {
    return __builtin_amdgcn_mfma_f32_16x16x16bf16_1k(a, b, c, 0, 0, 0);
}
#elif __has_builtin(__builtin_amdgcn_mfma_f32_16x16x16_bf16)
__device__ inline float4v mfma16(short4v a, short4v b, float4v c) {
    return __builtin_amdgcn_mfma_f32_16x16x16_bf16(a, b, c, 0, 0, 0);
}
#else
__device__ inline float4v mfma16(short4v a, short4v b, float4v c) {
    asm volatile("v_mfma_f32_16x16x16_bf16 %0, %1, %2, %0\n\ts_nop 4"
                 : "+v"(c) : "v"(a), "v"(b));
    return c;
}
#endif

// async global->LDS, 16 bytes per lane; LDS dest = wave-uniform base + lane*16
#define GLDS16(gp, lp) __builtin_amdgcn_global_load_lds( \
    (const __attribute__((address_space(1))) void*)(gp), \
    (__attribute__((address_space(3))) void*)(lp), 16, 0, 0)

// ---------------------------------------------------------------------------
__global__ __launch_bounds__(256) void cast_f32_bf16(
    const float* __restrict__ src, unsigned short* __restrict__ dst, int n4)
{
    int i = blockIdx.x * 256 + threadIdx.x;
    if (i >= n4) return;
    float4 f = ((const float4*)src)[i];
    ushort4 o;
    o.x = f2bf(f.x); o.y = f2bf(f.y); o.z = f2bf(f.z); o.w = f2bf(f.w);
    ((ushort4*)dst)[i] = o;
}

// ---------------------------------------------------------------------------
// bf16 MFMA GEMM: C[M][N] = A[M][K] @ W[N][K]^T + bias[N]. (m97 structure)
// ---------------------------------------------------------------------------
template <typename OT>
__global__ __launch_bounds__(256) void gemm_mfma_bt(
    const unsigned short* __restrict__ A, const unsigned short* __restrict__ W,
    const float* __restrict__ bias, OT* __restrict__ C,
    int M, int N, int K)
{
    __shared__ __align__(16) unsigned short As[128 * 32];
    __shared__ __align__(16) unsigned short Bs[128 * 32];

    const int t    = threadIdx.x;
    const int lane = t & 63;
    const int w    = t >> 6;
    const int row0 = blockIdx.y * 128;
    const int col0 = blockIdx.x * 128;
    const int wr   = (w & 1) * 64;
    const int wc   = (w >> 1) * 64;

    float4v acc[4][4];
#pragma unroll
    for (int i = 0; i < 4; ++i)
#pragma unroll
        for (int j = 0; j < 4; ++j) acc[i][j] = (float4v){0.f, 0.f, 0.f, 0.f};

    const int off1 = t * 16, off2 = 4096 + t * 16;
    const int r1 = off1 >> 6, c1 = off1 & 63;
    const int r2 = off2 >> 6, c2 = off2 & 63;
    const char* Ab = (const char*)A + (long)row0 * K * 2;
    const char* Wb = (const char*)W + (long)col0 * K * 2;
    const long  ks = (long)K * 2;

    for (int k0 = 0; k0 < K; k0 += 32) {
        const long kb = (long)k0 * 2;
        GLDS16(Ab + (long)r1 * ks + kb + c1, (char*)As + off1);
        GLDS16(Ab + (long)r2 * ks + kb + c2, (char*)As + off2);
        GLDS16(Wb + (long)r1 * ks + kb + c1, (char*)Bs + off1);
        GLDS16(Wb + (long)r2 * ks + kb + c2, (char*)Bs + off2);
        __syncthreads();

        short8 af[4], bfr[4];
#pragma unroll
        for (int i = 0; i < 4; ++i)
            af[i] = *(const short8*)&As[(wr + i * 16 + (lane & 15)) * 32 + (lane >> 4) * 8];
#pragma unroll
        for (int j = 0; j < 4; ++j)
            bfr[j] = *(const short8*)&Bs[(wc + j * 16 + (lane & 15)) * 32 + (lane >> 4) * 8];
#pragma unroll
        for (int i = 0; i < 4; ++i)
#pragma unroll
            for (int j = 0; j < 4; ++j)
                acc[i][j] = __builtin_amdgcn_mfma_f32_16x16x32_bf16(af[i], bfr[j], acc[i][j], 0, 0, 0);
        __syncthreads();
    }

    const int qd = lane >> 4, cl = lane & 15;
#pragma unroll
    for (int j = 0; j < 4; ++j) {
        const int col = col0 + wc + j * 16 + cl;
        const float bj = bias[col];
#pragma unroll
        for (int i = 0; i < 4; ++i) {
            const long rr = row0 + wr + i * 16 + qd * 4;
#pragma unroll
            for (int r = 0; r < 4; ++r) {
                float val = acc[i][j][r] + bj;
                if constexpr (std::is_same<OT, unsigned short>::value)
                    C[(rr + r) * (long)N + col] = f2bf(val);
                else
                    C[(rr + r) * (long)N + col] = val;
            }
        }
    }
}

// ---------------------------------------------------------------------------
// RMSNorm (q,k) + interleaved RoPE + split, bf16 in / bf16 out.
// q [bh][s][d] (pre-scaled 0.125), k [bh][s][d].
// v is emitted in MFMA A-FRAGMENT order per (bh, 64-kt tile):
//   tile blob (8192 B): offset = ((i*4+j)*64 + L)*8 bytes holds
//   V^T[i*16+(L&15)][j*16+(L>>4)*4 + 0..3]  (4 bf16)
// so flash can global_load_lds the blob and ds_read_b64 fragments directly.
// ---------------------------------------------------------------------------
__global__ __launch_bounds__(256) void norm_rope_split(
    const unsigned short* __restrict__ qkv,
    const float* __restrict__ cos_t, const float* __restrict__ sin_t,
    const float* __restrict__ qw, const float* __restrict__ kw,
    unsigned short* __restrict__ q, unsigned short* __restrict__ k,
    unsigned short* __restrict__ vt)
{
    __shared__ unsigned short vs[64][68];   // [d][s_local]

    const int lane = threadIdx.x & 63;
    const int w    = threadIdx.x >> 6;
    const int bh   = blockIdx.y;
    const int b    = bh >> 4;
    const int h    = bh & 15;
    const int s0   = blockIdx.x * 64;

    const float qwl = qw[lane], kwl = kw[lane];

#pragma unroll 4
    for (int i = 0; i < 16; ++i) {
        const int sl = w * 16 + i;
        const int s  = s0 + sl;
        const long bs = (long)b * SEQ + s;
        const unsigned short* base = qkv + bs * (3 * DIM) + h * 64 + lane;
        float qv = bf2f(base[0]);
        float kv = bf2f(base[DIM]);
        float vv = bf2f(base[2 * DIM]);

        float sq = qv * qv, sk = kv * kv;
#pragma unroll
        for (int m = 32; m; m >>= 1) {
            sq += __shfl_xor(sq, m, 64);
            sk += __shfl_xor(sk, m, 64);
        }
        float qn = qv * rsqrtf(sq * (1.f / 64.f) + EPS) * qwl;
        float kn = kv * rsqrtf(sk * (1.f / 64.f) + EPS) * kwl;

        float c  = cos_t[s * 64 + lane];
        float sn = sin_t[s * 64 + lane];
        float qp = __shfl_xor(qn, 1, 64);
        float kp = __shfl_xor(kn, 1, 64);
        float rq = (lane & 1) ? qp : -qp;
        float rk = (lane & 1) ? kp : -kp;
        float qo = (qn * c + rq * sn) * 0.125f;
        float ko = kn * c + rk * sn;

        const long off = ((long)bh * SEQ + s) * 64 + lane;
        q[off] = f2bf(qo);
        k[off] = f2bf(ko);
        vs[lane][sl] = f2bf(vv);
    }
    __syncthreads();

    // emit fragment-ordered tile: 4 chunks of 8 B per thread, coalesced
    unsigned short* dst = vt + (long)bh * SEQ * 64 + (long)blockIdx.x * 4096;
#pragma unroll
    for (int c = 0; c < 4; ++c) {
        const int idx = threadIdx.x + 256 * c;     // 0..1023
        const int f   = idx >> 6;                  // frag = i*4+j
        const int L   = idx & 63;
        const int d   = (f >> 2) * 16 + (L & 15);
        const int sl  = (f & 3) * 16 + (L >> 4) * 4;
        *(ushort4*)(dst + (long)idx * 4) = *(const ushort4*)&vs[d][sl];
    }
}

// ---------------------------------------------------------------------------
// MFMA flash attention, S^T formulation (no P LDS round-trip):
//   S^T chunks = K @ Q^T  (16x16x32, C-layout: lane cl,quad holds
//                          S[q=cl][kt=j*16+quad*4+r])
//   P packs in-register into the 16x16x16 B-fragment; O^T = V^T @ P^T.
// No-max softmax (rows RMS-normalized: |q.k|/8 <= 8, sums < 6.2e6).
// ---------------------------------------------------------------------------
__global__ __launch_bounds__(256) void flash_mfma(
    const unsigned short* __restrict__ q, const unsigned short* __restrict__ k,
    const unsigned short* __restrict__ vt, unsigned short* __restrict__ out)
{
    __shared__ __align__(16) unsigned short Qs[2][64 * 32];
    __shared__ __align__(16) unsigned short Ks[2][64 * 32];
    __shared__ __align__(16) unsigned short Vts[64 * 64];   // fragment order

    const int t    = threadIdx.x;
    const int lane = t & 63;
    const int w    = t >> 6;
    const int bh   = blockIdx.y;
    const int b    = bh >> 4;
    const int h    = bh & 15;
    const int q0   = blockIdx.x * 64;
    const int cl   = lane & 15;
    const int quad = lane >> 4;

    const char* qb  = (const char*)(q  + (long)bh * SEQ * 64);
    const char* kb  = (const char*)(k  + (long)bh * SEQ * 64);
    const char* vtb = (const char*)(vt + (long)bh * SEQ * 64);

    {
        const int off = t * 16, row = off >> 6, cb = off & 63;
#pragma unroll
        for (int hf = 0; hf < 2; ++hf)
            GLDS16(qb + (long)(q0 + row) * 128 + hf * 64 + cb, (char*)Qs[hf] + off);
    }
    __syncthreads();

    // Q as B-operand: lane holds Q[q=cl][d=quad*8+..], per 32-d half
    short8 aq[2];
#pragma unroll
    for (int c = 0; c < 2; ++c)
        aq[c] = *(const short8*)&Qs[c][(w * 16 + cl) * 32 + quad * 8];

    float4v o[4];
    float lacc = 0.f;
#pragma unroll
    for (int i = 0; i < 4; ++i) o[i] = (float4v){0.f, 0.f, 0.f, 0.f};

    const int soff = t * 16, srow = soff >> 6, scb = soff & 63;

    for (int kt = 0; kt < SEQ / 64; ++kt) {
#pragma unroll
        for (int hf = 0; hf < 2; ++hf)
            GLDS16(kb + (long)(kt * 64 + srow) * 128 + hf * 64 + scb, (char*)Ks[hf] + soff);
        GLDS16(vtb + (long)kt * 8192 + 0    + t * 16, (char*)Vts + t * 16);
        GLDS16(vtb + (long)kt * 8192 + 4096 + t * 16, (char*)Vts + 4096 + t * 16);
        __syncthreads();

        // S^T = K @ Q^T : 4 chunks of 16 kt-rows, K as A-operand
        float4v sa[4];
#pragma unroll
        for (int j = 0; j < 4; ++j) {
            short8 a0 = *(const short8*)&Ks[0][(j * 16 + cl) * 32 + quad * 8];
            short8 a1 = *(const short8*)&Ks[1][(j * 16 + cl) * 32 + quad * 8];
            float4v z = (float4v){0.f, 0.f, 0.f, 0.f};
            z = __builtin_amdgcn_mfma_f32_16x16x32_bf16(a0, aq[0], z, 0, 0, 0);
            sa[j] = __builtin_amdgcn_mfma_f32_16x16x32_bf16(a1, aq[1], z, 0, 0, 0);
        }

        // P = exp(S^T); row-partial into lacc; pack to 16x16x16 B-fragments
        short4v pa[4];
#pragma unroll
        for (int j = 0; j < 4; ++j) {
            float p0 = __expf(sa[j][0]), p1 = __expf(sa[j][1]);
            float p2 = __expf(sa[j][2]), p3 = __expf(sa[j][3]);
            lacc += (p0 + p1) + (p2 + p3);
            unsigned lo = pk2bf(p0, p1), hi = pk2bf(p2, p3);
            pa[j] = __builtin_bit_cast(short4v, ((unsigned long long)hi << 32) | lo);
        }

        // O^T += V^T @ P^T : 16x16x16 MFMAs, V^T fragments straight from LDS
#pragma unroll
        for (int i = 0; i < 4; ++i) {
#pragma unroll
            for (int j = 0; j < 4; ++j) {
                short4v vfr = *(const short4v*)((const char*)Vts + ((i * 4 + j) * 64 + lane) * 8);
                o[i] = mfma16(vfr, pa[j], o[i]);
            }
        }
        __syncthreads();
    }

    // row sum lives split across quads: butterfly over quad bits
    lacc += __shfl_xor(lacc, 16, 64);
    lacc += __shfl_xor(lacc, 32, 64);
    const float inv = 1.f / lacc;

    // lane holds O[q=cl][d=i*16+quad*4+r]; 8-B bf16 stores
    unsigned short* orow = out + ((long)b * SEQ + q0 + w * 16 + cl) * DIM + h * 64;
#pragma unroll
    for (int i = 0; i < 4; ++i) {
        unsigned lo = pk2bf(o[i][0] * inv, o[i][1] * inv);
        unsigned hi = pk2bf(o[i][2] * inv, o[i][3] * inv);
        ushort4 st = __builtin_bit_cast(ushort4, ((unsigned long long)hi << 32) | lo);
        *(ushort4*)(orow + i * 16 + quad * 4) = st;
    }
}

// ---------------------------------------------------------------------------
extern "C" void kernel_launch(void* const* d_in, const int* in_sizes, int n_in,
                              void* d_out, int out_size, void* d_ws, size_t ws_size,
                              hipStream_t stream)
{
    const float* x        = (const float*)d_in[0];
    const float* rope_cos = (const float*)d_in[1];
    const float* rope_sin = (const float*)d_in[2];
    const float* qkv_w    = (const float*)d_in[3];
    const float* qkv_b    = (const float*)d_in[4];
    const float* proj_w   = (const float*)d_in[5];
    const float* proj_b   = (const float*)d_in[6];
    const float* q_norm_w = (const float*)d_in[7];
    const float* k_norm_w = (const float*)d_in[8];
    float* outp = (float*)d_out;

    const int M = BATCH * SEQ;                         // 8192
    char* p = (char*)d_ws;
    unsigned short* qkvb  = (unsigned short*)p; p += (long)M * 3 * DIM * 2;
    unsigned short* xb    = (unsigned short*)p; p += (long)M * DIM * 2;
    unsigned short* qkvwb = (unsigned short*)p; p += (long)3 * DIM * DIM * 2;
    unsigned short* projwb= (unsigned short*)p; p += (long)DIM * DIM * 2;
    unsigned short* qb    = (unsigned short*)p; p += (long)M * DIM * 2;
    unsigned short* kbuf  = (unsigned short*)p; p += (long)M * DIM * 2;
    unsigned short* vtb   = (unsigned short*)p; p += (long)M * DIM * 2;
    unsigned short* attno = (unsigned short*)p; p += (long)M * DIM * 2;

    cast_f32_bf16<<<dim3((M * DIM / 4) / 256), 256, 0, stream>>>(x, xb, M * DIM / 4);
    cast_f32_bf16<<<dim3((3 * DIM * DIM / 4) / 256), 256, 0, stream>>>(qkv_w, qkvwb, 3 * DIM * DIM / 4);
    cast_f32_bf16<<<dim3((DIM * DIM / 4) / 256), 256, 0, stream>>>(proj_w, projwb, DIM * DIM / 4);

    gemm_mfma_bt<unsigned short><<<dim3(3 * DIM / 128, M / 128), 256, 0, stream>>>(
        xb, qkvwb, qkv_b, qkvb, M, 3 * DIM, DIM);

    norm_rope_split<<<dim3(SEQ / 64, BATCH * NH), 256, 0, stream>>>(
        qkvb, rope_cos, rope_sin, q_norm_w, k_norm_w, qb, kbuf, vtb);

    flash_mfma<<<dim3(SEQ / 64, BATCH * NH), 256, 0, stream>>>(qb, kbuf, vtb, attno);

    gemm_mfma_bt<float><<<dim3(DIM / 128, M / 128), 256, 0, stream>>>(
        attno, projwb, proj_b, outp, M, DIM, DIM);
}

// Round 5
// 347.702 us; speedup vs baseline: 8.4287x; 1.0533x over previous
//
#include <hip/hip_runtime.h>
#include <math.h>
#include <type_traits>

#define DIM 1024
#define NH 16
#define HD 64
#define BATCH 4
#define SEQ 2048
#define EPS 1e-6f

typedef __attribute__((ext_vector_type(8))) short short8;
typedef __attribute__((ext_vector_type(4))) short short4v;
typedef __attribute__((ext_vector_type(4))) float float4v;

// round-to-nearest-even f32 -> bf16 bits
__device__ inline unsigned short f2bf(float f) {
    unsigned u = __float_as_uint(f);
    u += 0x7FFF + ((u >> 16) & 1);
    return (unsigned short)(u >> 16);
}
__device__ inline float bf2f(unsigned short b) {
    return __uint_as_float(((unsigned)b) << 16);
}
// pack two f32 -> two bf16 (round-half-up): 2 adds + 1 perm
__device__ inline unsigned pk2bf(float lo, float hi) {
    unsigned ul = __float_as_uint(lo) + 0x8000u;
    unsigned uh = __float_as_uint(hi) + 0x8000u;
    return __builtin_amdgcn_perm(uh, ul, 0x07060302u);
}
__device__ inline unsigned short hu2bf(float f) {   // half-up single
    return (unsigned short)((__float_as_uint(f) + 0x8000u) >> 16);
}

// 16x16x16 bf16 MFMA
#if __has_builtin(__builtin_amdgcn_mfma_f32_16x16x16bf16_1k)
__device__ inline float4v mfma16(short4v a, short4v b, float4v c) {
    return __builtin_amdgcn_mfma_f32_16x16x16bf16_1k(a, b, c, 0, 0, 0);
}
#elif __has_builtin(__builtin_amdgcn_mfma_f32_16x16x16_bf16)
__device__ inline float4v mfma16(short4v a, short4v b, float4v c) {
    return __builtin_amdgcn_mfma_f32_16x16x16_bf16(a, b, c, 0, 0, 0);
}
#else
__device__ inline float4v mfma16(short4v a, short4v b, float4v c) {
    asm volatile("v_mfma_f32_16x16x16_bf16 %0, %1, %2, %0\n\ts_nop 4"
                 : "+v"(c) : "v"(a), "v"(b));
    return c;
}
#endif

#define GLDS16(gp, lp) __builtin_amdgcn_global_load_lds( \
    (const __attribute__((address_space(1))) void*)(gp), \
    (__attribute__((address_space(3))) void*)(lp), 16, 0, 0)

// ---------------------------------------------------------------------------
__global__ __launch_bounds__(256) void cast_f32_bf16(
    const float* __restrict__ src, unsigned short* __restrict__ dst, int n4)
{
    int i = blockIdx.x * 256 + threadIdx.x;
    if (i >= n4) return;
    float4 f = ((const float4*)src)[i];
    ushort4 o;
    o.x = f2bf(f.x); o.y = f2bf(f.y); o.z = f2bf(f.z); o.w = f2bf(f.w);
    ((ushort4*)dst)[i] = o;
}

// csT[d][s] = packed {bf16 cos (lo), bf16 sin (hi)} -- transposed so the GEMM
// epilogue reads 4 consecutive s per lane with one b128 load.
__global__ __launch_bounds__(256) void prep_cs(
    const float* __restrict__ cos_t, const float* __restrict__ sin_t,
    unsigned* __restrict__ csT)
{
    int tid = blockIdx.x * 256 + threadIdx.x;   // 0 .. SEQ*64-1
    int d = tid & 63, s = tid >> 6;             // coalesced reads
    float c = cos_t[s * 64 + d], sn = sin_t[s * 64 + d];
    csT[d * SEQ + s] = ((unsigned)f2bf(sn) << 16) | f2bf(c);
}

// ---------------------------------------------------------------------------
// Fused QKV GEMM: qkv = x @ W^T + b, then per-column-group epilogue:
//   q cols: RMS-norm (fp32 acc) + RoPE + 0.125 scale -> q[bh][s][d] bf16
//   k cols: RMS-norm + RoPE                          -> k[bh][s][d] bf16
//   v cols: direct register->fragment-order store    -> vt blobs (paired 16B)
// ---------------------------------------------------------------------------
__global__ __launch_bounds__(256) void gemm_qkv_fused(
    const unsigned short* __restrict__ A, const unsigned short* __restrict__ W,
    const float* __restrict__ bias, const unsigned* __restrict__ csT,
    const float* __restrict__ qw, const float* __restrict__ kw,
    unsigned short* __restrict__ q, unsigned short* __restrict__ k,
    unsigned short* __restrict__ vt)
{
    __shared__ __align__(16) unsigned short As[128 * 32];
    __shared__ __align__(16) unsigned short Bs[128 * 32];

    const int t    = threadIdx.x;
    const int lane = t & 63;
    const int w    = t >> 6;
    const int row0 = blockIdx.y * 128;
    const int col0 = blockIdx.x * 128;      // 0..2943
    const int wr   = (w & 1) * 64;
    const int wc   = (w >> 1) * 64;
    const int cl   = lane & 15;
    const int quad = lane >> 4;

    float4v acc[4][4];
#pragma unroll
    for (int i = 0; i < 4; ++i)
#pragma unroll
        for (int j = 0; j < 4; ++j) acc[i][j] = (float4v){0.f, 0.f, 0.f, 0.f};

    const int off1 = t * 16, off2 = 4096 + t * 16;
    const int r1 = off1 >> 6, c1 = off1 & 63;
    const int r2 = off2 >> 6, c2 = off2 & 63;
    const char* Ab = (const char*)A + (long)row0 * DIM * 2;
    const char* Wb = (const char*)W + (long)col0 * DIM * 2;
    const long  ks = DIM * 2;

    for (int k0 = 0; k0 < DIM; k0 += 32) {
        const long kb = (long)k0 * 2;
        GLDS16(Ab + (long)r1 * ks + kb + c1, (char*)As + off1);
        GLDS16(Ab + (long)r2 * ks + kb + c2, (char*)As + off2);
        GLDS16(Wb + (long)r1 * ks + kb + c1, (char*)Bs + off1);
        GLDS16(Wb + (long)r2 * ks + kb + c2, (char*)Bs + off2);
        __syncthreads();

        short8 af[4], bfr[4];
#pragma unroll
        for (int i = 0; i < 4; ++i)
            af[i] = *(const short8*)&As[(wr + i * 16 + cl) * 32 + quad * 8];
#pragma unroll
        for (int j = 0; j < 4; ++j)
            bfr[j] = *(const short8*)&Bs[(wc + j * 16 + cl) * 32 + quad * 8];
#pragma unroll
        for (int i = 0; i < 4; ++i)
#pragma unroll
            for (int j = 0; j < 4; ++j)
                acc[i][j] = __builtin_amdgcn_mfma_f32_16x16x32_bf16(af[i], bfr[j], acc[i][j], 0, 0, 0);
        __syncthreads();
    }

    const int gcol  = col0 + wc;            // wave col base (mult of 64)
    const int b     = row0 >> 11;
    const int srow0 = (row0 & 2047) + wr;   // s base of wave (mult of 64)

    // bias (per j, lane cl)
    float bj[4];
#pragma unroll
    for (int j = 0; j < 4; ++j) bj[j] = bias[gcol + j * 16 + cl];

    if (gcol < 2 * DIM) {
        // ---- q or k: bias add, RMS norm on fp32 acc, RoPE, store bf16 ----
        const bool isq = (gcol < DIM);
        const int  h   = (isq ? gcol : gcol - DIM) >> 6;
        const float* nw = isq ? qw : kw;
        const float scale = isq ? 0.125f : 1.0f;
        unsigned short* dst = (isq ? q : k) + ((long)(b * NH + h) * SEQ) * 64;

#pragma unroll
        for (int i = 0; i < 4; ++i)
#pragma unroll
            for (int j = 0; j < 4; ++j)
#pragma unroll
                for (int r = 0; r < 4; ++r) acc[i][j][r] += bj[j];

        float rinv[4][4];
#pragma unroll
        for (int i = 0; i < 4; ++i)
#pragma unroll
            for (int r = 0; r < 4; ++r) {
                float ss = acc[i][0][r] * acc[i][0][r];
                ss = fmaf(acc[i][1][r], acc[i][1][r], ss);
                ss = fmaf(acc[i][2][r], acc[i][2][r], ss);
                ss = fmaf(acc[i][3][r], acc[i][3][r], ss);
                ss += __shfl_xor(ss, 1, 64);
                ss += __shfl_xor(ss, 2, 64);
                ss += __shfl_xor(ss, 4, 64);
                ss += __shfl_xor(ss, 8, 64);
                rinv[i][r] = rsqrtf(ss * (1.f / 64.f) + EPS) * scale;
            }

        float nwj[4];
#pragma unroll
        for (int j = 0; j < 4; ++j) nwj[j] = nw[j * 16 + cl];

#pragma unroll
        for (int i = 0; i < 4; ++i) {
            const int sb = srow0 + i * 16 + quad * 4;
#pragma unroll
            for (int j = 0; j < 4; ++j) {
                const int d = j * 16 + cl;
                uint4 u4 = *(const uint4*)(csT + (long)d * SEQ + sb);
#pragma unroll
                for (int r = 0; r < 4; ++r) {
                    // note: scale folded into rinv (rope is linear in x)
                    float qn = acc[i][j][r] * rinv[i][r] * nwj[j];
                    float p  = __shfl_xor(qn, 1, 64);
                    float pr = (cl & 1) ? p : -p;
                    unsigned u = (r == 0) ? u4.x : (r == 1) ? u4.y : (r == 2) ? u4.z : u4.w;
                    float c  = bf2f((unsigned short)(u & 0xffff));
                    float sn = bf2f((unsigned short)(u >> 16));
                    float ov = fmaf(qn, c, pr * sn);
                    dst[(long)(sb + r) * 64 + d] = hu2bf(ov);
                }
            }
        }
    } else {
        // ---- v: direct fragment-order store (registers ARE the A-fragment) --
        // fragment (fi=j, fj=i); pairs along fj -> 16-B units:
        // blob offset (shorts) = (j*2 + i/2)*512 + lane*8 (+4 for odd i)
        const int h = (gcol - 2 * DIM) >> 6;
        unsigned short* vdst = vt + (long)(b * NH + h) * SEQ * 64
                                  + (long)(srow0 >> 6) * 4096;
#pragma unroll
        for (int j = 0; j < 4; ++j)
#pragma unroll
            for (int ip = 0; ip < 2; ++ip) {
                const int i0 = 2 * ip;
                uint4 st;
                st.x = pk2bf(acc[i0][j][0] + bj[j],     acc[i0][j][1] + bj[j]);
                st.y = pk2bf(acc[i0][j][2] + bj[j],     acc[i0][j][3] + bj[j]);
                st.z = pk2bf(acc[i0 + 1][j][0] + bj[j], acc[i0 + 1][j][1] + bj[j]);
                st.w = pk2bf(acc[i0 + 1][j][2] + bj[j], acc[i0 + 1][j][3] + bj[j]);
                *(uint4*)(vdst + (j * 2 + ip) * 512 + lane * 8) = st;
            }
    }
}

// ---------------------------------------------------------------------------
// bf16 MFMA GEMM (proj): C[M][N] = A[M][K] @ W[N][K]^T + bias[N], fp32 out.
// ---------------------------------------------------------------------------
template <typename OT>
__global__ __launch_bounds__(256) void gemm_mfma_bt(
    const unsigned short* __restrict__ A, const unsigned short* __restrict__ W,
    const float* __restrict__ bias, OT* __restrict__ C,
    int M, int N, int K)
{
    __shared__ __align__(16) unsigned short As[128 * 32];
    __shared__ __align__(16) unsigned short Bs[128 * 32];

    const int t    = threadIdx.x;
    const int lane = t & 63;
    const int w    = t >> 6;
    const int row0 = blockIdx.y * 128;
    const int col0 = blockIdx.x * 128;
    const int wr   = (w & 1) * 64;
    const int wc   = (w >> 1) * 64;

    float4v acc[4][4];
#pragma unroll
    for (int i = 0; i < 4; ++i)
#pragma unroll
        for (int j = 0; j < 4; ++j) acc[i][j] = (float4v){0.f, 0.f, 0.f, 0.f};

    const int off1 = t * 16, off2 = 4096 + t * 16;
    const int r1 = off1 >> 6, c1 = off1 & 63;
    const int r2 = off2 >> 6, c2 = off2 & 63;
    const char* Ab = (const char*)A + (long)row0 * K * 2;
    const char* Wb = (const char*)W + (long)col0 * K * 2;
    const long  ks = (long)K * 2;

    for (int k0 = 0; k0 < K; k0 += 32) {
        const long kb = (long)k0 * 2;
        GLDS16(Ab + (long)r1 * ks + kb + c1, (char*)As + off1);
        GLDS16(Ab + (long)r2 * ks + kb + c2, (char*)As + off2);
        GLDS16(Wb + (long)r1 * ks + kb + c1, (char*)Bs + off1);
        GLDS16(Wb + (long)r2 * ks + kb + c2, (char*)Bs + off2);
        __syncthreads();

        short8 af[4], bfr[4];
#pragma unroll
        for (int i = 0; i < 4; ++i)
            af[i] = *(const short8*)&As[(wr + i * 16 + (lane & 15)) * 32 + (lane >> 4) * 8];
#pragma unroll
        for (int j = 0; j < 4; ++j)
            bfr[j] = *(const short8*)&Bs[(wc + j * 16 + (lane & 15)) * 32 + (lane >> 4) * 8];
#pragma unroll
        for (int i = 0; i < 4; ++i)
#pragma unroll
            for (int j = 0; j < 4; ++j)
                acc[i][j] = __builtin_amdgcn_mfma_f32_16x16x32_bf16(af[i], bfr[j], acc[i][j], 0, 0, 0);
        __syncthreads();
    }

    const int qd = lane >> 4, cl = lane & 15;
#pragma unroll
    for (int j = 0; j < 4; ++j) {
        const int col = col0 + wc + j * 16 + cl;
        const float bj = bias[col];
#pragma unroll
        for (int i = 0; i < 4; ++i) {
            const long rr = row0 + wr + i * 16 + qd * 4;
#pragma unroll
            for (int r = 0; r < 4; ++r) {
                float val = acc[i][j][r] + bj;
                if constexpr (std::is_same<OT, unsigned short>::value)
                    C[(rr + r) * (long)N + col] = f2bf(val);
                else
                    C[(rr + r) * (long)N + col] = val;
            }
        }
    }
}

// ---------------------------------------------------------------------------
// MFMA flash attention, S^T formulation, no-max softmax.
// V blob is fragment-PAIR packed: b128 gives 2 fragments per read.
// ---------------------------------------------------------------------------
__global__ __launch_bounds__(256) void flash_mfma(
    const unsigned short* __restrict__ q, const unsigned short* __restrict__ k,
    const unsigned short* __restrict__ vt, unsigned short* __restrict__ out)
{
    __shared__ __align__(16) unsigned short Qs[2][64 * 32];
    __shared__ __align__(16) unsigned short Ks[2][64 * 32];
    __shared__ __align__(16) unsigned short Vts[64 * 64];

    const int t    = threadIdx.x;
    const int lane = t & 63;
    const int w    = t >> 6;
    const int bh   = blockIdx.y;
    const int b    = bh >> 4;
    const int h    = bh & 15;
    const int q0   = blockIdx.x * 64;
    const int cl   = lane & 15;
    const int quad = lane >> 4;

    const char* qb  = (const char*)(q  + (long)bh * SEQ * 64);
    const char* kb  = (const char*)(k  + (long)bh * SEQ * 64);
    const char* vtb = (const char*)(vt + (long)bh * SEQ * 64);

    {
        const int off = t * 16, row = off >> 6, cb = off & 63;
#pragma unroll
        for (int hf = 0; hf < 2; ++hf)
            GLDS16(qb + (long)(q0 + row) * 128 + hf * 64 + cb, (char*)Qs[hf] + off);
    }
    __syncthreads();

    short8 aq[2];
#pragma unroll
    for (int c = 0; c < 2; ++c)
        aq[c] = *(const short8*)&Qs[c][(w * 16 + cl) * 32 + quad * 8];

    float4v o[4];
    float lacc = 0.f;
#pragma unroll
    for (int i = 0; i < 4; ++i) o[i] = (float4v){0.f, 0.f, 0.f, 0.f};

    const int soff = t * 16, srow = soff >> 6, scb = soff & 63;

    for (int kt = 0; kt < SEQ / 64; ++kt) {
#pragma unroll
        for (int hf = 0; hf < 2; ++hf)
            GLDS16(kb + (long)(kt * 64 + srow) * 128 + hf * 64 + scb, (char*)Ks[hf] + soff);
        GLDS16(vtb + (long)kt * 8192 + 0    + t * 16, (char*)Vts + t * 16);
        GLDS16(vtb + (long)kt * 8192 + 4096 + t * 16, (char*)Vts + 4096 + t * 16);
        __syncthreads();

        // S^T = K @ Q^T
        float4v sa[4];
#pragma unroll
        for (int j = 0; j < 4; ++j) {
            short8 a0 = *(const short8*)&Ks[0][(j * 16 + cl) * 32 + quad * 8];
            short8 a1 = *(const short8*)&Ks[1][(j * 16 + cl) * 32 + quad * 8];
            float4v z = (float4v){0.f, 0.f, 0.f, 0.f};
            z = __builtin_amdgcn_mfma_f32_16x16x32_bf16(a0, aq[0], z, 0, 0, 0);
            sa[j] = __builtin_amdgcn_mfma_f32_16x16x32_bf16(a1, aq[1], z, 0, 0, 0);
        }

        // P = exp(S^T), pack into 16x16x16 B-fragments in-register
        short4v pa[4];
#pragma unroll
        for (int j = 0; j < 4; ++j) {
            float p0 = __expf(sa[j][0]), p1 = __expf(sa[j][1]);
            float p2 = __expf(sa[j][2]), p3 = __expf(sa[j][3]);
            lacc += (p0 + p1) + (p2 + p3);
            unsigned lo = pk2bf(p0, p1), hi = pk2bf(p2, p3);
            pa[j] = __builtin_bit_cast(short4v, ((unsigned long long)hi << 32) | lo);
        }

        // O^T += V^T @ P^T : paired fragments, b128 reads
#pragma unroll
        for (int fi = 0; fi < 4; ++fi) {
#pragma unroll
            for (int fjp = 0; fjp < 2; ++fjp) {
                short8 vv = *(const short8*)&Vts[(fi * 2 + fjp) * 512 + lane * 8];
                short4v va = __builtin_shufflevector(vv, vv, 0, 1, 2, 3);
                short4v vb = __builtin_shufflevector(vv, vv, 4, 5, 6, 7);
                o[fi] = mfma16(va, pa[2 * fjp], o[fi]);
                o[fi] = mfma16(vb, pa[2 * fjp + 1], o[fi]);
            }
        }
        __syncthreads();
    }

    lacc += __shfl_xor(lacc, 16, 64);
    lacc += __shfl_xor(lacc, 32, 64);
    const float inv = 1.f / lacc;

    unsigned short* orow = out + ((long)b * SEQ + q0 + w * 16 + cl) * DIM + h * 64;
#pragma unroll
    for (int i = 0; i < 4; ++i) {
        unsigned lo = pk2bf(o[i][0] * inv, o[i][1] * inv);
        unsigned hi = pk2bf(o[i][2] * inv, o[i][3] * inv);
        ushort4 st = __builtin_bit_cast(ushort4, ((unsigned long long)hi << 32) | lo);
        *(ushort4*)(orow + i * 16 + quad * 4) = st;
    }
}

// ---------------------------------------------------------------------------
extern "C" void kernel_launch(void* const* d_in, const int* in_sizes, int n_in,
                              void* d_out, int out_size, void* d_ws, size_t ws_size,
                              hipStream_t stream)
{
    const float* x        = (const float*)d_in[0];
    const float* rope_cos = (const float*)d_in[1];
    const float* rope_sin = (const float*)d_in[2];
    const float* qkv_w    = (const float*)d_in[3];
    const float* qkv_b    = (const float*)d_in[4];
    const float* proj_w   = (const float*)d_in[5];
    const float* proj_b   = (const float*)d_in[6];
    const float* q_norm_w = (const float*)d_in[7];
    const float* k_norm_w = (const float*)d_in[8];
    float* outp = (float*)d_out;

    const int M = BATCH * SEQ;                         // 8192
    char* p = (char*)d_ws;
    unsigned short* xb    = (unsigned short*)p; p += (long)M * DIM * 2;
    unsigned short* qkvwb = (unsigned short*)p; p += (long)3 * DIM * DIM * 2;
    unsigned short* projwb= (unsigned short*)p; p += (long)DIM * DIM * 2;
    unsigned short* qb    = (unsigned short*)p; p += (long)M * DIM * 2;
    unsigned short* kbuf  = (unsigned short*)p; p += (long)M * DIM * 2;
    unsigned short* vtb   = (unsigned short*)p; p += (long)M * DIM * 2;
    unsigned short* attno = (unsigned short*)p; p += (long)M * DIM * 2;
    unsigned*       csT   = (unsigned*)p;       p += (long)SEQ * 64 * 4;

    prep_cs<<<dim3(SEQ * 64 / 256), 256, 0, stream>>>(rope_cos, rope_sin, csT);
    cast_f32_bf16<<<dim3((M * DIM / 4) / 256), 256, 0, stream>>>(x, xb, M * DIM / 4);
    cast_f32_bf16<<<dim3((3 * DIM * DIM / 4) / 256), 256, 0, stream>>>(qkv_w, qkvwb, 3 * DIM * DIM / 4);
    cast_f32_bf16<<<dim3((DIM * DIM / 4) / 256), 256, 0, stream>>>(proj_w, projwb, DIM * DIM / 4);

    // fused QKV GEMM + bias + RMSNorm + RoPE + v fragment layout
    gemm_qkv_fused<<<dim3(3 * DIM / 128, M / 128), 256, 0, stream>>>(
        xb, qkvwb, qkv_b, csT, q_norm_w, k_norm_w, qb, kbuf, vtb);

    flash_mfma<<<dim3(SEQ / 64, BATCH * NH), 256, 0, stream>>>(qb, kbuf, vtb, attno);

    gemm_mfma_bt<float><<<dim3(DIM / 128, M / 128), 256, 0, stream>>>(
        attno, projwb, proj_b, outp, M, DIM, DIM);
}

// Round 6
// 302.936 us; speedup vs baseline: 9.6743x; 1.1478x over previous
//
#include <hip/hip_runtime.h>
#include <math.h>
#include <type_traits>

#define DIM 1024
#define NH 16
#define HD 64
#define BATCH 4
#define SEQ 2048
#define EPS 1e-6f

typedef __attribute__((ext_vector_type(8))) short short8;
typedef __attribute__((ext_vector_type(4))) short short4v;
typedef __attribute__((ext_vector_type(4))) float float4v;

// f32 -> bf16 round-to-nearest-even
__device__ inline unsigned short f2bf(float f) {
    unsigned u = __float_as_uint(f);
    u += 0x7FFF + ((u >> 16) & 1);
    return (unsigned short)(u >> 16);
}
__device__ inline float bf2f(unsigned short b) {
    return __uint_as_float(((unsigned)b) << 16);
}
// pack two f32 -> two bf16 (round-half-up): 2 adds + 1 perm
__device__ inline unsigned pk2bf(float lo, float hi) {
    unsigned ul = __float_as_uint(lo) + 0x8000u;
    unsigned uh = __float_as_uint(hi) + 0x8000u;
    return __builtin_amdgcn_perm(uh, ul, 0x07060302u);
}

#if __has_builtin(__builtin_amdgcn_exp2f)
#define EXP2F(x) __builtin_amdgcn_exp2f(x)
#else
#define EXP2F(x) exp2f(x)
#endif

// 16x16x16 bf16 MFMA
#if __has_builtin(__builtin_amdgcn_mfma_f32_16x16x16bf16_1k)
__device__ inline float4v mfma16(short4v a, short4v b, float4v c) {
    return __builtin_amdgcn_mfma_f32_16x16x16bf16_1k(a, b, c, 0, 0, 0);
}
#elif __has_builtin(__builtin_amdgcn_mfma_f32_16x16x16_bf16)
__device__ inline float4v mfma16(short4v a, short4v b, float4v c) {
    return __builtin_amdgcn_mfma_f32_16x16x16_bf16(a, b, c, 0, 0, 0);
}
#else
__device__ inline float4v mfma16(short4v a, short4v b, float4v c) {
    asm volatile("v_mfma_f32_16x16x16_bf16 %0, %1, %2, %0\n\ts_nop 4"
                 : "+v"(c) : "v"(a), "v"(b));
    return c;
}
#endif

#define GLDS16(gp, lp) __builtin_amdgcn_global_load_lds( \
    (const __attribute__((address_space(1))) void*)(gp), \
    (__attribute__((address_space(3))) void*)(lp), 16, 0, 0)

// ---------------------------------------------------------------------------
// One prep kernel: x cast | qkv_w cast (q/k rows PERMUTED for in-register
// RoPE pairing) | proj_w cast | packed cos/sin table.
// Permutation: new col c=(j,cl) within a head holds true d=(j&1)+2*cl+32*(j>>1),
// so the RoPE pair (2a,2a+1) sits in one lane at adjacent j registers.
// ---------------------------------------------------------------------------
__global__ __launch_bounds__(256) void prep_all(
    const float* __restrict__ x, const float* __restrict__ qkv_w,
    const float* __restrict__ proj_w,
    const float* __restrict__ cos_t, const float* __restrict__ sin_t,
    unsigned short* __restrict__ xb, unsigned short* __restrict__ qkvwb,
    unsigned short* __restrict__ projwb, unsigned* __restrict__ csP)
{
    const int bid = blockIdx.x;
    if (bid < 8192) {                       // x: 8192*1024 elems, 1 float4/thr
        int i = bid * 256 + threadIdx.x;
        float4 f = ((const float4*)x)[i];
        ushort4 o;
        o.x = f2bf(f.x); o.y = f2bf(f.y); o.z = f2bf(f.z); o.w = f2bf(f.w);
        ((ushort4*)xb)[i] = o;
    } else if (bid < 8192 + 3072) {         // qkv_w: one row per block
        const int rn = bid - 8192;
        int ro = rn;
        if (rn < 2048) {
            const int head = rn >> 6, c = rn & 63, j = c >> 4, cl = c & 15;
            ro = (head << 6) + ((j & 1) + 2 * cl + 32 * (j >> 1));
        }
        float4 f = ((const float4*)(qkv_w + (long)ro * DIM))[threadIdx.x];
        ushort4 o;
        o.x = f2bf(f.x); o.y = f2bf(f.y); o.z = f2bf(f.z); o.w = f2bf(f.w);
        ((ushort4*)(qkvwb + (long)rn * DIM))[threadIdx.x] = o;
    } else if (bid < 8192 + 3072 + 1024) {  // proj_w
        int i = (bid - 11264) * 256 + threadIdx.x;
        float4 f = ((const float4*)proj_w)[i];
        ushort4 o;
        o.x = f2bf(f.x); o.y = f2bf(f.y); o.z = f2bf(f.z); o.w = f2bf(f.w);
        ((ushort4*)projwb)[i] = o;
    } else {                                // csP[a][s], a=freq idx 0..31
        int i = (bid - 12288) * 256 + threadIdx.x;   // 32*2048
        int a = i >> 11, s = i & 2047;
        float c = cos_t[s * 64 + 2 * a], sn = sin_t[s * 64 + 2 * a];
        csP[a * SEQ + s] = ((unsigned)f2bf(sn) << 16) | f2bf(c);
    }
}

// ---------------------------------------------------------------------------
// Fused QKV GEMM + bias + RMSNorm + RoPE (in-register via permuted W) + V
// fragment-order store. q pre-scaled by 0.125*log2(e) for exp2 softmax.
// ---------------------------------------------------------------------------
__global__ __launch_bounds__(256) void gemm_qkv_fused(
    const unsigned short* __restrict__ A, const unsigned short* __restrict__ W,
    const float* __restrict__ bias, const unsigned* __restrict__ csP,
    const float* __restrict__ qw, const float* __restrict__ kw,
    unsigned short* __restrict__ q, unsigned short* __restrict__ k,
    unsigned short* __restrict__ vt)
{
    __shared__ __align__(16) unsigned short As[128 * 32];
    __shared__ __align__(16) unsigned short Bs[128 * 32];

    const int t    = threadIdx.x;
    const int lane = t & 63;
    const int w    = t >> 6;
    const int row0 = blockIdx.y * 128;
    const int col0 = blockIdx.x * 128;
    const int wr   = (w & 1) * 64;
    const int wc   = (w >> 1) * 64;
    const int cl   = lane & 15;
    const int quad = lane >> 4;

    float4v acc[4][4];
#pragma unroll
    for (int i = 0; i < 4; ++i)
#pragma unroll
        for (int j = 0; j < 4; ++j) acc[i][j] = (float4v){0.f, 0.f, 0.f, 0.f};

    const int off1 = t * 16, off2 = 4096 + t * 16;
    const int r1 = off1 >> 6, c1 = off1 & 63;
    const int r2 = off2 >> 6, c2 = off2 & 63;
    const char* Ab = (const char*)A + (long)row0 * DIM * 2;
    const char* Wb = (const char*)W + (long)col0 * DIM * 2;
    const long  ks = DIM * 2;

    for (int k0 = 0; k0 < DIM; k0 += 32) {
        const long kb = (long)k0 * 2;
        GLDS16(Ab + (long)r1 * ks + kb + c1, (char*)As + off1);
        GLDS16(Ab + (long)r2 * ks + kb + c2, (char*)As + off2);
        GLDS16(Wb + (long)r1 * ks + kb + c1, (char*)Bs + off1);
        GLDS16(Wb + (long)r2 * ks + kb + c2, (char*)Bs + off2);
        __syncthreads();

        short8 af[4], bfr[4];
#pragma unroll
        for (int i = 0; i < 4; ++i)
            af[i] = *(const short8*)&As[(wr + i * 16 + cl) * 32 + quad * 8];
#pragma unroll
        for (int j = 0; j < 4; ++j)
            bfr[j] = *(const short8*)&Bs[(wc + j * 16 + cl) * 32 + quad * 8];
#pragma unroll
        for (int i = 0; i < 4; ++i)
#pragma unroll
            for (int j = 0; j < 4; ++j)
                acc[i][j] = __builtin_amdgcn_mfma_f32_16x16x32_bf16(af[i], bfr[j], acc[i][j], 0, 0, 0);
        __syncthreads();
    }

    const int gcol  = col0 + wc;            // head base col (mult of 64)
    const int b     = row0 >> 11;
    const int srow0 = (row0 & 2047) + wr;

    if (gcol < 2 * DIM) {
        // ---- q/k: permuted cols -> true d = (j&1)+2cl+32(j>>1) ----
        const bool isq = (gcol < DIM);
        const int  h   = (isq ? gcol : gcol - DIM) >> 6;
        const float* nw = isq ? qw : kw;
        const float scale = isq ? 0.180336880f : 1.0f;   // 0.125*log2(e)
        unsigned short* dst = (isq ? q : k) + (long)(b * NH + h) * SEQ * 64;

        float bjv[4];
#pragma unroll
        for (int j = 0; j < 4; ++j)
            bjv[j] = bias[gcol + (j & 1) + 2 * cl + 32 * (j >> 1)];
#pragma unroll
        for (int i = 0; i < 4; ++i)
#pragma unroll
            for (int j = 0; j < 4; ++j)
#pragma unroll
                for (int r = 0; r < 4; ++r) acc[i][j][r] += bjv[j];

        float rinv[4][4];
#pragma unroll
        for (int i = 0; i < 4; ++i)
#pragma unroll
            for (int r = 0; r < 4; ++r) {
                float ss = acc[i][0][r] * acc[i][0][r];
                ss = fmaf(acc[i][1][r], acc[i][1][r], ss);
                ss = fmaf(acc[i][2][r], acc[i][2][r], ss);
                ss = fmaf(acc[i][3][r], acc[i][3][r], ss);
                ss += __shfl_xor(ss, 1, 64);
                ss += __shfl_xor(ss, 2, 64);
                ss += __shfl_xor(ss, 4, 64);
                ss += __shfl_xor(ss, 8, 64);
                rinv[i][r] = rsqrtf(ss * (1.f / 64.f) + EPS) * scale;
            }

        const float nwe[2] = { nw[2 * cl],     nw[32 + 2 * cl] };
        const float nwo[2] = { nw[2 * cl + 1], nw[33 + 2 * cl] };

#pragma unroll
        for (int i = 0; i < 4; ++i) {
            const int sb = srow0 + i * 16 + quad * 4;
#pragma unroll
            for (int jp = 0; jp < 2; ++jp) {
                uint4 cs4 = *(const uint4*)(csP + (long)(jp * 16 + cl) * SEQ + sb);
#pragma unroll
                for (int r = 0; r < 4; ++r) {
                    float g  = rinv[i][r];
                    float xe = acc[i][2 * jp][r]     * g * nwe[jp];
                    float xo = acc[i][2 * jp + 1][r] * g * nwo[jp];
                    unsigned u = (r == 0) ? cs4.x : (r == 1) ? cs4.y : (r == 2) ? cs4.z : cs4.w;
                    float c  = bf2f((unsigned short)(u & 0xffff));
                    float sn = bf2f((unsigned short)(u >> 16));
                    float oe = fmaf(xe, c, -(xo * sn));
                    float oo = fmaf(xo, c,   xe * sn);
                    *(unsigned*)(dst + (long)(sb + r) * 64 + jp * 32 + 2 * cl) = pk2bf(oe, oo);
                }
            }
        }
    } else {
        // ---- v: direct fragment-order store (paired 16-B units) ----
        const int h = (gcol - 2 * DIM) >> 6;
        float bjv[4];
#pragma unroll
        for (int j = 0; j < 4; ++j) bjv[j] = bias[gcol + j * 16 + cl];
        unsigned short* vdst = vt + (long)(b * NH + h) * SEQ * 64
                                  + (long)(srow0 >> 6) * 4096;
#pragma unroll
        for (int j = 0; j < 4; ++j)
#pragma unroll
            for (int ip = 0; ip < 2; ++ip) {
                const int i0 = 2 * ip;
                uint4 st;
                st.x = pk2bf(acc[i0][j][0] + bjv[j],     acc[i0][j][1] + bjv[j]);
                st.y = pk2bf(acc[i0][j][2] + bjv[j],     acc[i0][j][3] + bjv[j]);
                st.z = pk2bf(acc[i0 + 1][j][0] + bjv[j], acc[i0 + 1][j][1] + bjv[j]);
                st.w = pk2bf(acc[i0 + 1][j][2] + bjv[j], acc[i0 + 1][j][3] + bjv[j]);
                *(uint4*)(vdst + (j * 2 + ip) * 512 + lane * 8) = st;
            }
    }
}

// ---------------------------------------------------------------------------
// proj GEMM (unchanged m97 structure, fp32 out)
// ---------------------------------------------------------------------------
__global__ __launch_bounds__(256) void gemm_proj(
    const unsigned short* __restrict__ A, const unsigned short* __restrict__ W,
    const float* __restrict__ bias, float* __restrict__ C)
{
    __shared__ __align__(16) unsigned short As[128 * 32];
    __shared__ __align__(16) unsigned short Bs[128 * 32];

    const int t    = threadIdx.x;
    const int lane = t & 63;
    const int w    = t >> 6;
    const int row0 = blockIdx.y * 128;
    const int col0 = blockIdx.x * 128;
    const int wr   = (w & 1) * 64;
    const int wc   = (w >> 1) * 64;

    float4v acc[4][4];
#pragma unroll
    for (int i = 0; i < 4; ++i)
#pragma unroll
        for (int j = 0; j < 4; ++j) acc[i][j] = (float4v){0.f, 0.f, 0.f, 0.f};

    const int off1 = t * 16, off2 = 4096 + t * 16;
    const int r1 = off1 >> 6, c1 = off1 & 63;
    const int r2 = off2 >> 6, c2 = off2 & 63;
    const char* Ab = (const char*)A + (long)row0 * DIM * 2;
    const char* Wb = (const char*)W + (long)col0 * DIM * 2;
    const long  ks = DIM * 2;

    for (int k0 = 0; k0 < DIM; k0 += 32) {
        const long kb = (long)k0 * 2;
        GLDS16(Ab + (long)r1 * ks + kb + c1, (char*)As + off1);
        GLDS16(Ab + (long)r2 * ks + kb + c2, (char*)As + off2);
        GLDS16(Wb + (long)r1 * ks + kb + c1, (char*)Bs + off1);
        GLDS16(Wb + (long)r2 * ks + kb + c2, (char*)Bs + off2);
        __syncthreads();

        short8 af[4], bfr[4];
#pragma unroll
        for (int i = 0; i < 4; ++i)
            af[i] = *(const short8*)&As[(wr + i * 16 + (lane & 15)) * 32 + (lane >> 4) * 8];
#pragma unroll
        for (int j = 0; j < 4; ++j)
            bfr[j] = *(const short8*)&Bs[(wc + j * 16 + (lane & 15)) * 32 + (lane >> 4) * 8];
#pragma unroll
        for (int i = 0; i < 4; ++i)
#pragma unroll
            for (int j = 0; j < 4; ++j)
                acc[i][j] = __builtin_amdgcn_mfma_f32_16x16x32_bf16(af[i], bfr[j], acc[i][j], 0, 0, 0);
        __syncthreads();
    }

    const int qd = lane >> 4, cl = lane & 15;
#pragma unroll
    for (int j = 0; j < 4; ++j) {
        const int col = col0 + wc + j * 16 + cl;
        const float bj = bias[col];
#pragma unroll
        for (int i = 0; i < 4; ++i) {
            const long rr = row0 + wr + i * 16 + qd * 4;
#pragma unroll
            for (int r = 0; r < 4; ++r)
                C[(rr + r) * (long)DIM + col] = acc[i][j][r] + bj;
        }
    }
}

// ---------------------------------------------------------------------------
// MFMA flash attention. Q-tile=128 (each wave: 2 q-groups of 16), S^T form,
// exp2 softmax (log2e pre-folded into q), row sums via ones-vector MFMA.
// ---------------------------------------------------------------------------
__global__ __launch_bounds__(256) void flash_mfma(
    const unsigned short* __restrict__ q, const unsigned short* __restrict__ k,
    const unsigned short* __restrict__ vt, unsigned short* __restrict__ out)
{
    __shared__ __align__(16) unsigned short Qs[2][128 * 32];
    __shared__ __align__(16) unsigned short Ks[2][64 * 32];
    __shared__ __align__(16) unsigned short Vts[64 * 64];

    const int t    = threadIdx.x;
    const int lane = t & 63;
    const int w    = t >> 6;
    const int bh   = blockIdx.y;
    const int b    = bh >> 4;
    const int h    = bh & 15;
    const int q0   = blockIdx.x * 128;
    const int cl   = lane & 15;
    const int quad = lane >> 4;

    const char* qb  = (const char*)(q  + (long)bh * SEQ * 64);
    const char* kb  = (const char*)(k  + (long)bh * SEQ * 64);
    const char* vtb = (const char*)(vt + (long)bh * SEQ * 64);

    // stage Q tile (128 rows x 2 halves)
#pragma unroll
    for (int rd = 0; rd < 2; ++rd) {
        const int off = rd * 4096 + t * 16;
        const int row = off >> 6, cb = off & 63;
#pragma unroll
        for (int hf = 0; hf < 2; ++hf)
            GLDS16(qb + (long)(q0 + row) * 128 + hf * 64 + cb, (char*)Qs[hf] + off);
    }
    __syncthreads();

    short8 aq[2][2];
#pragma unroll
    for (int qg = 0; qg < 2; ++qg)
#pragma unroll
        for (int hf = 0; hf < 2; ++hf)
            aq[qg][hf] = *(const short8*)&Qs[hf][(w * 32 + qg * 16 + cl) * 32 + quad * 8];

    const short4v ones = (short4v){(short)0x3F80, (short)0x3F80, (short)0x3F80, (short)0x3F80};

    float4v o[2][4], o4[2];
#pragma unroll
    for (int qg = 0; qg < 2; ++qg) {
        o4[qg] = (float4v){0.f, 0.f, 0.f, 0.f};
#pragma unroll
        for (int i = 0; i < 4; ++i) o[qg][i] = (float4v){0.f, 0.f, 0.f, 0.f};
    }

    const int soff = t * 16, srow = soff >> 6, scb = soff & 63;

    for (int kt = 0; kt < SEQ / 64; ++kt) {
#pragma unroll
        for (int hf = 0; hf < 2; ++hf)
            GLDS16(kb + (long)(kt * 64 + srow) * 128 + hf * 64 + scb, (char*)Ks[hf] + soff);
        GLDS16(vtb + (long)kt * 8192 + t * 16,        (char*)Vts + t * 16);
        GLDS16(vtb + (long)kt * 8192 + 4096 + t * 16, (char*)Vts + 4096 + t * 16);
        __syncthreads();

        short4v pa[2][4];
#pragma unroll
        for (int j = 0; j < 4; ++j) {
            short8 a0 = *(const short8*)&Ks[0][(j * 16 + cl) * 32 + quad * 8];
            short8 a1 = *(const short8*)&Ks[1][(j * 16 + cl) * 32 + quad * 8];
#pragma unroll
            for (int qg = 0; qg < 2; ++qg) {
                float4v z = (float4v){0.f, 0.f, 0.f, 0.f};
                z = __builtin_amdgcn_mfma_f32_16x16x32_bf16(a0, aq[qg][0], z, 0, 0, 0);
                float4v s = __builtin_amdgcn_mfma_f32_16x16x32_bf16(a1, aq[qg][1], z, 0, 0, 0);
                float p0 = EXP2F(s[0]), p1 = EXP2F(s[1]);
                float p2 = EXP2F(s[2]), p3 = EXP2F(s[3]);
                unsigned lo = pk2bf(p0, p1), hi = pk2bf(p2, p3);
                pa[qg][j] = __builtin_bit_cast(short4v, ((unsigned long long)hi << 32) | lo);
                o4[qg] = mfma16(ones, pa[qg][j], o4[qg]);   // row sums on MFMA pipe
            }
        }

        // O^T += V^T @ P^T (V fragments shared across both q-groups)
#pragma unroll
        for (int fi = 0; fi < 4; ++fi) {
#pragma unroll
            for (int fjp = 0; fjp < 2; ++fjp) {
                short8 vv = *(const short8*)&Vts[(fi * 2 + fjp) * 512 + lane * 8];
                short4v va = __builtin_shufflevector(vv, vv, 0, 1, 2, 3);
                short4v vb = __builtin_shufflevector(vv, vv, 4, 5, 6, 7);
#pragma unroll
                for (int qg = 0; qg < 2; ++qg) {
                    o[qg][fi] = mfma16(va, pa[qg][2 * fjp],     o[qg][fi]);
                    o[qg][fi] = mfma16(vb, pa[qg][2 * fjp + 1], o[qg][fi]);
                }
            }
        }
        __syncthreads();
    }

#pragma unroll
    for (int qg = 0; qg < 2; ++qg) {
        const float inv = 1.f / o4[qg][0];   // replicated across rows; q=cl
        unsigned short* orow = out + ((long)b * SEQ + q0 + w * 32 + qg * 16 + cl) * DIM + h * 64;
#pragma unroll
        for (int i = 0; i < 4; ++i) {
            unsigned lo = pk2bf(o[qg][i][0] * inv, o[qg][i][1] * inv);
            unsigned hi = pk2bf(o[qg][i][2] * inv, o[qg][i][3] * inv);
            ushort4 st = __builtin_bit_cast(ushort4, ((unsigned long long)hi << 32) | lo);
            *(ushort4*)(orow + i * 16 + quad * 4) = st;
        }
    }
}

// ---------------------------------------------------------------------------
extern "C" void kernel_launch(void* const* d_in, const int* in_sizes, int n_in,
                              void* d_out, int out_size, void* d_ws, size_t ws_size,
                              hipStream_t stream)
{
    const float* x        = (const float*)d_in[0];
    const float* rope_cos = (const float*)d_in[1];
    const float* rope_sin = (const float*)d_in[2];
    const float* qkv_w    = (const float*)d_in[3];
    const float* qkv_b    = (const float*)d_in[4];
    const float* proj_w   = (const float*)d_in[5];
    const float* proj_b   = (const float*)d_in[6];
    const float* q_norm_w = (const float*)d_in[7];
    const float* k_norm_w = (const float*)d_in[8];
    float* outp = (float*)d_out;

    const int M = BATCH * SEQ;
    char* p = (char*)d_ws;
    unsigned short* xb    = (unsigned short*)p; p += (long)M * DIM * 2;
    unsigned short* qkvwb = (unsigned short*)p; p += (long)3 * DIM * DIM * 2;
    unsigned short* projwb= (unsigned short*)p; p += (long)DIM * DIM * 2;
    unsigned short* qb    = (unsigned short*)p; p += (long)M * DIM * 2;
    unsigned short* kbuf  = (unsigned short*)p; p += (long)M * DIM * 2;
    unsigned short* vtb   = (unsigned short*)p; p += (long)M * DIM * 2;
    unsigned short* attno = (unsigned short*)p; p += (long)M * DIM * 2;
    unsigned*       csP   = (unsigned*)p;       p += (long)32 * SEQ * 4;

    prep_all<<<dim3(12544), 256, 0, stream>>>(
        x, qkv_w, proj_w, rope_cos, rope_sin, xb, qkvwb, projwb, csP);

    gemm_qkv_fused<<<dim3(3 * DIM / 128, M / 128), 256, 0, stream>>>(
        xb, qkvwb, qkv_b, csP, q_norm_w, k_norm_w, qb, kbuf, vtb);

    flash_mfma<<<dim3(SEQ / 128, BATCH * NH), 256, 0, stream>>>(qb, kbuf, vtb, attno);

    gemm_proj<<<dim3(DIM / 128, M / 128), 256, 0, stream>>>(
        attno, projwb, proj_b, outp);
}